// Round 11
// baseline (2244.013 us; speedup 1.0000x reference)
//
#include <hip/hip_runtime.h>
#include <hip/hip_bf16.h>

typedef __hip_bfloat16 bf16;
using bf16x8 = __attribute__((ext_vector_type(8))) short;
using f32x4  = __attribute__((ext_vector_type(4))) float;

#define kNEG 1.0e9f

__device__ __forceinline__ float b2f(bf16 x){ return __bfloat162float(x); }
__device__ __forceinline__ bf16  f2b(float x){ return __float2bfloat16(x); }

#define GLDS16(gp, lp) __builtin_amdgcn_global_load_lds( \
    (const __attribute__((address_space(1))) void*)(gp), \
    (__attribute__((address_space(3))) void*)(lp), 16, 0, 0)

__device__ __forceinline__ void unpack8(uint4 u, float* f){
  f[0]=__uint_as_float(u.x<<16); f[1]=__uint_as_float(u.x&0xffff0000u);
  f[2]=__uint_as_float(u.y<<16); f[3]=__uint_as_float(u.y&0xffff0000u);
  f[4]=__uint_as_float(u.z<<16); f[5]=__uint_as_float(u.z&0xffff0000u);
  f[6]=__uint_as_float(u.w<<16); f[7]=__uint_as_float(u.w&0xffff0000u);
}

// ---------------- embedding + LN ----------------
__global__ __launch_bounds__(256)
void embed_ln(const int* __restrict__ ids, const float* __restrict__ wemb,
              const float* __restrict__ pemb, const float* __restrict__ lns,
              const float* __restrict__ lnb, float* __restrict__ hout,
              bf16* __restrict__ hbout)
{
  const int row = blockIdx.x;
  const int tid = threadIdx.x;
  const int wave = tid >> 6, lane = tid & 63;
  const int id = ids[row];
  float x[3];
  #pragma unroll
  for (int p=0;p<3;p++){
    int i = tid + p*256;
    x[p] = wemb[(size_t)id*768 + i] + pemb[(size_t)row*768 + i];
  }
  float s1 = x[0]+x[1]+x[2];
  float s2 = x[0]*x[0]+x[1]*x[1]+x[2]*x[2];
  #pragma unroll
  for (int m=32;m>=1;m>>=1){ s1 += __shfl_xor(s1,m); s2 += __shfl_xor(s2,m); }
  __shared__ float red[8];
  if (lane==0){ red[wave]=s1; red[4+wave]=s2; }
  __syncthreads();
  s1 = red[0]+red[1]+red[2]+red[3];
  s2 = red[4]+red[5]+red[6]+red[7];
  float mu = s1*(1.0f/768.0f);
  float var = s2*(1.0f/768.0f) - mu*mu;
  float rs = rsqrtf(var + 1e-5f);
  #pragma unroll
  for (int p=0;p<3;p++){
    int i = tid + p*256;
    float y = (x[p]-mu)*rs*lns[i] + lnb[i];
    hout[(size_t)row*768+i] = y;
    hbout[(size_t)row*768+i] = f2b(y);
  }
}

// ---------------- residual add (four partials) + LN ----------------
__global__ __launch_bounds__(256)
void add_ln(const float* __restrict__ res, const float* __restrict__ pf,
            const float* __restrict__ lns, const float* __restrict__ lnb,
            float* __restrict__ hout, bf16* __restrict__ hbout)
{
  const size_t MN = (size_t)2048*768;
  const int row = blockIdx.x;
  const int tid = threadIdx.x;
  const int wave = tid >> 6, lane = tid & 63;
  float x[3];
  #pragma unroll
  for (int p=0;p<3;p++){
    int i = tid + p*256;
    size_t idx = (size_t)row*768+i;
    x[p] = res[idx] + ((pf[idx] + pf[MN+idx]) + (pf[2*MN+idx] + pf[3*MN+idx]));
  }
  float s1 = x[0]+x[1]+x[2];
  float s2 = x[0]*x[0]+x[1]*x[1]+x[2]*x[2];
  #pragma unroll
  for (int m=32;m>=1;m>>=1){ s1 += __shfl_xor(s1,m); s2 += __shfl_xor(s2,m); }
  __shared__ float red[8];
  if (lane==0){ red[wave]=s1; red[4+wave]=s2; }
  __syncthreads();
  s1 = red[0]+red[1]+red[2]+red[3];
  s2 = red[4]+red[5]+red[6]+red[7];
  float mu = s1*(1.0f/768.0f);
  float var = s2*(1.0f/768.0f) - mu*mu;
  float rs = rsqrtf(var + 1e-5f);
  #pragma unroll
  for (int p=0;p<3;p++){
    int i = tid + p*256;
    float y = (x[p]-mu)*rs*lns[i] + lnb[i];
    hout[(size_t)row*768+i] = y;
    hbout[(size_t)row*768+i] = f2b(y);
  }
}

// ---------------- ALL-layer weight transpose -> swizzled BK-64 TILED layout ----------------
__global__ __launch_bounds__(256)
void prep_all(const float* __restrict__ Wq, const float* __restrict__ Wk,
              const float* __restrict__ Wv, const float* __restrict__ Wkg,
              const float* __restrict__ Wvg, const float* __restrict__ Wo,
              const float* __restrict__ Wf1, const float* __restrict__ Wf2,
              const float* __restrict__ bq, const float* __restrict__ bk,
              const float* __restrict__ bv, const float* __restrict__ bkg,
              const float* __restrict__ bvg,
              bf16* __restrict__ WcatT, bf16* __restrict__ WoT,
              bf16* __restrict__ Wf1T, bf16* __restrict__ Wf2T,
              float* __restrict__ bcat)
{
  const int b = blockIdx.x;
  const int l = blockIdx.y;
  const int tid = threadIdx.x;
  const size_t oHH = (size_t)l*768*768;
  const size_t oHF = (size_t)l*768*3072;
  const size_t oH  = (size_t)l*768;
  if (b >= 504) {
    int i = (b-504)*256 + tid;   // 0..3839
    int which = i / 768, j = i - which*768;
    float v;
    if      (which==0) v = bq[oH+j] * 0.125f;
    else if (which==1) v = bk[oH+j];
    else if (which==2) v = bv[oH+j];
    else if (which==3) v = bkg[oH+j];
    else               v = bvg[oH+j];
    bcat[(size_t)l*3840 + i] = v;
    return;
  }
  const float* src; bf16* dst; int N, KT64, p0, tk, k0, n0; float scale = 1.0f;
  if (b < 180) {
    int wsel = b/36, tile = b - wsel*36;
    int tkk = tile/3, tn = tile - tkk*3;
    if      (wsel==0){ src=Wq+oHH;  scale=0.125f; }
    else if (wsel==1){ src=Wk+oHH; }
    else if (wsel==2){ src=Wv+oHH; }
    else if (wsel==3){ src=Wkg+oHH; }
    else             { src=Wvg+oHH; }
    dst = WcatT + (size_t)l*5*768*768;
    N=768; KT64=12; k0=tkk*64; n0=tn*256; p0 = wsel*6 + tn*2; tk = tkk;
  } else if (b < 216) {
    int tile = b-180, tkk = tile/3, tn = tile - tkk*3;
    src = Wo+oHH; dst = WoT + (size_t)l*768*768;
    N=768; KT64=12; k0=tkk*64; n0=tn*256; p0 = tn*2; tk = tkk;
  } else if (b < 360) {
    int tile = b-216, tkk = tile/12, tn = tile - tkk*12;
    src = Wf1+oHF; dst = Wf1T + (size_t)l*768*3072;
    N=3072; KT64=12; k0=tkk*64; n0=tn*256; p0 = tn*2; tk = tkk;
  } else {
    int tile = b-360, tkk = tile/3, tn = tile - tkk*3;
    src = Wf2+oHF; dst = Wf2T + (size_t)l*768*3072;
    N=768; KT64=48; k0=tkk*64; n0=tn*256; p0 = tn*2; tk = tkk;
  }

  __shared__ bf16 t[64][264];
  const int wave = tid>>6, lane = tid&63;
  float4 v[16];
  #pragma unroll
  for (int i=0;i<16;i++){
    int r = i*4 + wave;
    v[i] = *(const float4*)&src[(size_t)(k0+r)*N + n0 + lane*4];
  }
  #pragma unroll
  for (int i=0;i<16;i++){
    int r = i*4 + wave;
    union { ushort4 u; bf16 h[4]; } pk;
    pk.h[0]=f2b(v[i].x*scale); pk.h[1]=f2b(v[i].y*scale);
    pk.h[2]=f2b(v[i].z*scale); pk.h[3]=f2b(v[i].w*scale);
    *(ushort4*)&t[r][lane*4] = pk.u;
  }
  __syncthreads();
  const int rr = tid>>1, half = tid&1;
  const int r7 = rr & 7;
  #pragma unroll
  for (int c=0;c<4;c++){
    const int pp = c>>1, tt = c&1;
    union { uint4 u[2]; bf16 h[16]; } pk;
    #pragma unroll
    for (int j=0;j<16;j++)
      pk.h[j] = t[tt*32 + half*16 + j][pp*128 + rr];
    bf16* base = dst + ((size_t)(p0+pp)*KT64 + tk)*8192 + rr*64;
    const int g0 = tt*4 + half*2;
    *(uint4*)(base + (((g0  ) ^ r7)<<3)) = pk.u[0];
    *(uint4*)(base + (((g0+1) ^ r7)<<3)) = pk.u[1];
  }
}

// ---------------- MFMA GEMM (BK=64, depth-2 counted-vmcnt, XOR-swizzled LDS) ----------------
template<int OUTF, int OUTB, int GELU, int KSPLIT, int VT>
__global__ __launch_bounds__(256)
void gemm_bt(const bf16* __restrict__ A, const bf16* __restrict__ Bt,
             const float* __restrict__ bias,
             float* __restrict__ outf, bf16* __restrict__ outb,
             bf16* __restrict__ vt,
             int M, int N, int K)
{
  __shared__ bf16 As[2][128*64];
  __shared__ bf16 Bs[2][128*64];
  const int tid  = threadIdx.x;
  const int lane = tid & 63;
  const int wave = tid >> 6;
  const int wm = wave >> 1, wn = wave & 1;
  const int gx = gridDim.x, nwg = gx*gridDim.y;
  const int w  = blockIdx.y*gx + blockIdx.x;
  const int cpx = nwg >> 3;
  const int sw = (w & 7)*cpx + (w >> 3);
  const int bm = sw % gx, bn = sw / gx;
  const int bz = (KSPLIT>1) ? blockIdx.z : 0;
  const int fr = lane & 15;
  const int fk = lane >> 4;
  const int x7 = fr & 7;
  const int Ks = K / KSPLIT;
  const int nt = Ks >> 6;
  const int kbeg = bz * Ks;
  const int KT64 = K >> 6;

  const bf16* pa[4];
  int ldsA[4];
  #pragma unroll
  for (int i=0;i<4;i++){
    int s = i*256 + tid;
    int row = s >> 3, k8l = s & 7;
    pa[i] = A + (size_t)(bm*128 + row)*K + kbeg + ((k8l ^ (row&7))<<3);
    ldsA[i] = s*8;
  }
  const bf16* pB = Bt + ((size_t)bn*KT64 + (kbeg>>6))*8192;

  f32x4 acc[4][4];
  const f32x4 zero = {0.f,0.f,0.f,0.f};
  #pragma unroll
  for (int i=0;i<4;i++)
    #pragma unroll
    for (int j=0;j<4;j++) acc[i][j] = zero;

  #pragma unroll
  for (int i=0;i<4;i++) GLDS16(pa[i], &As[0][ldsA[i]]);
  #pragma unroll
  for (int i=0;i<4;i++){ int o=(i*256+tid)*8; GLDS16(pB+o, &Bs[0][o]); }
  if (nt > 1) {
    #pragma unroll
    for (int i=0;i<4;i++) GLDS16(pa[i]+64, &As[1][ldsA[i]]);
    #pragma unroll
    for (int i=0;i<4;i++){ int o=(i*256+tid)*8; GLDS16(pB+8192+o, &Bs[1][o]); }
  }

  for (int t = 0; t < nt; ++t) {
    const int cur = t & 1;
    if (t < nt-1) asm volatile("s_waitcnt vmcnt(8)" ::: "memory");
    else          asm volatile("s_waitcnt vmcnt(0)" ::: "memory");
    __builtin_amdgcn_s_barrier();
    __builtin_amdgcn_sched_barrier(0);

    bf16x8 af[2][4], bfr[2][4];
    #pragma unroll
    for (int kk=0;kk<2;kk++){
      #pragma unroll
      for (int m=0;m<4;m++)
        af[kk][m] = *reinterpret_cast<const bf16x8*>(
            &As[cur][(wm*64 + m*16 + fr)*64 + ((((kk<<2)+fk) ^ x7)<<3)]);
      #pragma unroll
      for (int n=0;n<4;n++)
        bfr[kk][n] = *reinterpret_cast<const bf16x8*>(
            &Bs[cur][(wn*64 + n*16 + fr)*64 + ((((kk<<2)+fk) ^ x7)<<3)]);
    }
    __builtin_amdgcn_s_setprio(1);
    #pragma unroll
    for (int kk=0;kk<2;kk++)
      #pragma unroll
      for (int m=0;m<4;m++)
        #pragma unroll
        for (int n=0;n<4;n++)
          acc[m][n] = __builtin_amdgcn_mfma_f32_16x16x32_bf16(af[kk][m], bfr[kk][n], acc[m][n], 0,0,0);
    __builtin_amdgcn_s_setprio(0);

    __builtin_amdgcn_s_barrier();
    __builtin_amdgcn_sched_barrier(0);
    if (t+2 < nt) {
      #pragma unroll
      for (int i=0;i<4;i++) GLDS16(pa[i] + (size_t)(t+2)*64, &As[cur][ldsA[i]]);
      #pragma unroll
      for (int i=0;i<4;i++){ int o=(i*256+tid)*8;
        GLDS16(pB + (size_t)(t+2)*8192 + o, &Bs[cur][o]); }
    }
  }

  const int row0 = bm*128 + wm*64 + (lane>>4)*4;
  const int col0 = bn*128 + wn*64 + fr;
  float* outfz = OUTF ? (outf + (size_t)bz*M*N) : nullptr;
  #pragma unroll
  for (int n=0;n<4;n++){
    const int col = col0 + n*16;
    const float bv = (bz==0) ? bias[col] : 0.f;
    #pragma unroll
    for (int m=0;m<4;m++){
      const int r0 = row0 + m*16;
      union { ushort4 u; bf16 h[4]; } pk;
      #pragma unroll
      for (int r=0;r<4;r++){
        float x = acc[m][n][r] + bv;
        if (GELU) x = 0.5f*x*(1.0f + erff(x*0.70710678118f));
        size_t idx = (size_t)(r0+r)*N + col;
        pk.h[r] = f2b(x);
        if (OUTF) outfz[idx] = x;
        if (OUTB) outb[idx] = pk.h[r];
      }
      if (VT) {
        if (col >= 1536 && col < 2304)
          *(ushort4*)&vt[(size_t)(col-1536)*2048 + r0] = pk.u;
      }
    }
  }
}

// ---------------- band + global attention (merged launch) ----------------
// Band path uses max-free softmax: scores are bounded (|S| << 80) so
// exp(S)/sum(exp(S)) is exact; masked lanes get exp(-1e9)=0 exactly.
__global__ __launch_bounds__(256)
void band_attn(const bf16* __restrict__ qkv, const bf16* __restrict__ Vt,
               const float* __restrict__ h0, const float* __restrict__ Wqg,
               const float* __restrict__ bqg,
               const int* __restrict__ amask, const int* __restrict__ gmask,
               bf16* __restrict__ attn)
{
  const int c = blockIdx.x, n = blockIdx.y, rg = blockIdx.z;
  const int tid = threadIdx.x, wave = tid>>6, lane = tid&63;

  if (rg == 4) {
    if (c != 0) return;
    __shared__ float sg[2048];
    __shared__ float qh[64];
    __shared__ float redg[8];
    __shared__ float partg[4][64];
    {
      const int d = tid & 63;
      const int w = tid >> 6;
      const float* wp = Wqg + (size_t)(w*192)*768 + n*64 + d;
      float a = 0.f;
      #pragma unroll 8
      for (int k=0;k<192;k++) a += h0[w*192+k] * wp[(size_t)k*768];
      partg[w][d] = a;
    }
    __syncthreads();
    if (tid < 64)
      qh[tid] = (partg[0][tid]+partg[1][tid]+partg[2][tid]+partg[3][tid] + bqg[n*64+tid]) * 0.125f;
    __syncthreads();

    float smax = -3.0e38f;
    for (int p=0;p<8;p++){
      int s = p*256 + tid;
      const uint4* kr = (const uint4*)(qkv + (size_t)s*3840 + 2304 + n*64);
      float acc = 0.f;
      #pragma unroll
      for (int d8=0; d8<8; d8++){
        float f[8]; unpack8(kr[d8], f);
        #pragma unroll
        for (int e=0;e<8;e++) acc += f[e]*qh[d8*8+e];
      }
      if (amask[s] == 0) acc = -kNEG;
      sg[s] = acc;
      smax = fmaxf(smax, acc);
    }
    #pragma unroll
    for (int mk=32; mk>=1; mk>>=1) smax = fmaxf(smax, __shfl_xor(smax, mk));
    if (lane==0) redg[wave] = smax;
    __syncthreads();
    smax = fmaxf(fmaxf(redg[0],redg[1]),fmaxf(redg[2],redg[3]));
    float ssum = 0.f;
    for (int p=0;p<8;p++){
      int s = p*256 + tid;
      float e = __expf(sg[s]-smax);
      sg[s] = e;
      ssum += e;
    }
    #pragma unroll
    for (int mk=32; mk>=1; mk>>=1) ssum += __shfl_xor(ssum, mk);
    if (lane==0) redg[4+wave] = ssum;
    __syncthreads();
    float total = redg[4]+redg[5]+redg[6]+redg[7];
    __syncthreads();

    float o0=0.f,o1=0.f,o2=0.f,o3=0.f;
    const int base = wave*512;
    for (int s = base; s < base+512; s+=4){
      o0 += sg[s]   * b2f(qkv[(size_t)s*3840     + 3072 + n*64 + lane]);
      o1 += sg[s+1] * b2f(qkv[(size_t)(s+1)*3840 + 3072 + n*64 + lane]);
      o2 += sg[s+2] * b2f(qkv[(size_t)(s+2)*3840 + 3072 + n*64 + lane]);
      o3 += sg[s+3] * b2f(qkv[(size_t)(s+3)*3840 + 3072 + n*64 + lane]);
    }
    partg[wave][lane] = (o0+o1)+(o2+o3);
    __syncthreads();
    if (tid < 64) {
      float oo = (partg[0][tid]+partg[1][tid]+partg[2][tid]+partg[3][tid]) / total;
      attn[n*64+tid] = f2b(oo);
    }
    return;
  }

  // ---- band path ----
  const int fr = lane & 15, fk = lane >> 4;
  const int jj = tid >> 2, seg = tid & 3;

  __shared__ __attribute__((aligned(16))) bf16 q_s[64][72];
  __shared__ __attribute__((aligned(16))) bf16 k_s[2][64][72];
  __shared__ __attribute__((aligned(16))) bf16 vt_s[2][64][72];
  __shared__ __attribute__((aligned(16))) bf16 p_s[4][16][72];
  __shared__ int  okk_s[768];
  __shared__ float kv0[2][64];

  {
    const uint4* src = (const uint4*)(qkv + (size_t)(c*256 + rg*64 + jj)*3840 + n*64 + seg*16);
    *(uint4*)&q_s[jj][seg*16]   = src[0];
    *(uint4*)&q_s[jj][seg*16+8] = src[1];
  }
  #pragma unroll
  for (int p=0;p<3;p++){
    int j = tid + p*256;
    int kpos = c*256 + j - 256;
    int ok = 0;
    if (kpos >= 0 && kpos < 2048) ok = (amask[kpos] != 0) && (gmask[kpos] == 0);
    okk_s[j] = ok;
  }
  if (tid < 64)       kv0[0][tid]    = b2f(qkv[768  + n*64 + tid]);
  else if (tid < 128) kv0[1][tid-64] = b2f(qkv[1536 + n*64 + (tid-64)]);

  auto loadK = [&](int kt, uint4& a, uint4& b){
    int kpos = c*256 + kt*64 + jj - 256;
    int kq = kpos < 0 ? 0 : (kpos > 2047 ? 2047 : kpos);
    const uint4* ks = (const uint4*)(qkv + (size_t)kq*3840 + 768 + n*64 + seg*16);
    a = ks[0]; b = ks[1];
  };
  auto loadV = [&](int kt, uint4& a, uint4& b){
    int base = c*256 + kt*64 - 256;
    int sb = (base < 0 || base > 2048-64) ? 0 : base;
    const uint4* vs = (const uint4*)(Vt + (size_t)(n*64 + jj)*2048 + sb + seg*8);
    a = vs[0]; b = vs[4];
  };

  // clip to tiles with at least one in-range key
  const int kt_lo = (c==0) ? ((rg > 4) ? rg : 4) : rg;
  int kt_hi = rg+8 < 11 ? rg+8 : 11;
  const int clip = (2303 - c*256) >> 6;
  if (kt_hi > clip) kt_hi = clip;

  uint4 ka,kb,va,vb;
  loadK(kt_lo,ka,kb); loadV(kt_lo,va,vb);
  *(uint4*)&k_s[0][jj][seg*16]    = ka;
  *(uint4*)&k_s[0][jj][seg*16+8]  = kb;
  *(uint4*)&vt_s[0][jj][seg*8]    = va;
  *(uint4*)&vt_s[0][jj][seg*8+32] = vb;

  float lsum[4];
  f32x4 out[4];
  const f32x4 zero = {0.f,0.f,0.f,0.f};
  #pragma unroll
  for (int r=0;r<4;r++) lsum[r] = 0.f;
  #pragma unroll
  for (int dt=0;dt<4;dt++) out[dt] = zero;

  int cur = 0;
  for (int kt = kt_lo; kt <= kt_hi; kt++) {
    const bool pf = (kt < kt_hi);
    if (pf){ loadK(kt+1,ka,kb); loadV(kt+1,va,vb); }
    __syncthreads();

    f32x4 s[4];
    #pragma unroll
    for (int ct=0;ct<4;ct++) s[ct] = zero;
    __builtin_amdgcn_s_setprio(1);
    #pragma unroll
    for (int ks=0;ks<2;ks++){
      bf16x8 aq = *reinterpret_cast<const bf16x8*>(&q_s[wave*16 + fr][ks*32 + fk*8]);
      #pragma unroll
      for (int ct=0;ct<4;ct++){
        bf16x8 bk = *reinterpret_cast<const bf16x8*>(&k_s[cur][ct*16 + fr][ks*32 + fk*8]);
        s[ct] = __builtin_amdgcn_mfma_f32_16x16x32_bf16(aq, bk, s[ct], 0,0,0);
      }
    }
    __builtin_amdgcn_s_setprio(0);
    const int qbase = rg*64 + wave*16 + fk*4;
    // max-free softmax: P = exp(S) directly; masked -> exp(-1e9) = 0
    #pragma unroll
    for (int ct=0;ct<4;ct++){
      int j = kt*64 + ct*16 + fr;
      int okj = okk_s[j];
      #pragma unroll
      for (int r=0;r<4;r++){
        unsigned rel = (unsigned)(j - (qbase + r));
        float sv = (okj && rel <= 512u) ? s[ct][r] : -kNEG;
        float p = __expf(sv);
        lsum[r] += p;
        p_s[wave][fk*4 + r][ct*16 + fr] = f2b(p);
      }
    }
    __builtin_amdgcn_s_setprio(1);
    #pragma unroll
    for (int ks=0;ks<2;ks++){
      bf16x8 ap = *reinterpret_cast<const bf16x8*>(&p_s[wave][fr][ks*32 + fk*8]);
      #pragma unroll
      for (int dt=0;dt<4;dt++){
        bf16x8 bv = *reinterpret_cast<const bf16x8*>(&vt_s[cur][dt*16 + fr][ks*32 + fk*8]);
        out[dt] = __builtin_amdgcn_mfma_f32_16x16x32_bf16(ap, bv, out[dt], 0,0,0);
      }
    }
    __builtin_amdgcn_s_setprio(0);

    if (pf){
      *(uint4*)&k_s[cur^1][jj][seg*16]    = ka;
      *(uint4*)&k_s[cur^1][jj][seg*16+8]  = kb;
      *(uint4*)&vt_s[cur^1][jj][seg*8]    = va;
      *(uint4*)&vt_s[cur^1][jj][seg*8+32] = vb;
      cur ^= 1;
    }
  }

  // single end-of-loop row-sum reduce + global column + finalize
  const bool okg = (amask[0] != 0);
  #pragma unroll
  for (int r=0;r<4;r++){
    const int row16 = fk*4 + r;
    float ts = lsum[r];
    #pragma unroll
    for (int mk=8; mk>=1; mk>>=1) ts += __shfl_xor(ts, mk);
    float sp = 0.f;
    #pragma unroll
    for (int e=0;e<4;e++){
      int d = fr*4 + e;
      sp += b2f(q_s[wave*16 + row16][d]) * kv0[0][d];
    }
    #pragma unroll
    for (int mk=8; mk>=1; mk>>=1) sp += __shfl_xor(sp, mk);
    float pg = okg ? __expf(sp) : 0.f;
    float lf = ts + pg;
    const int srow = c*256 + rg*64 + wave*16 + row16;
    if (srow != 0) {
      #pragma unroll
      for (int dt=0;dt<4;dt++){
        int d = dt*16 + fr;
        float o = (out[dt][r] + pg*kv0[1][d]) / lf;
        attn[(size_t)srow*768 + n*64 + d] = f2b(o);
      }
    }
  }
}

// ---------------- head: tanh(h0 @ dw + db) @ ow + ob ----------------
__global__ __launch_bounds__(768)
void head(const float* __restrict__ h0, const float* __restrict__ dw,
          const float* __restrict__ db, const float* __restrict__ ow,
          const float* __restrict__ ob, float* __restrict__ out)
{
  __shared__ float y[768];
  const int tid = threadIdx.x;
  float acc = 0.f;
  #pragma unroll 8
  for (int k=0;k<768;k++) acc += h0[k]*dw[(size_t)k*768 + tid];
  y[tid] = tanhf(acc + db[tid]);
  __syncthreads();
  if (tid < 256) {
    float a = 0.f;
    #pragma unroll 8
    for (int k=0;k<768;k++) a += y[k]*ow[(size_t)k*256 + tid];
    out[tid] = a + ob[tid];
  }
}

// ---------------- host ----------------
extern "C" void kernel_launch(void* const* d_in, const int* in_sizes, int n_in,
                              void* d_out, int out_size, void* d_ws, size_t ws_size,
                              hipStream_t stream)
{
  const int*   ids   = (const int*)d_in[0];
  const int*   amask = (const int*)d_in[1];
  const int*   gmask = (const int*)d_in[2];
  const float* wemb  = (const float*)d_in[3];
  const float* pemb  = (const float*)d_in[4];
  const float* elns  = (const float*)d_in[5];
  const float* elnb  = (const float*)d_in[6];
  const float* Wq    = (const float*)d_in[7];
  const float* bq    = (const float*)d_in[8];
  const float* Wk    = (const float*)d_in[9];
  const float* bk    = (const float*)d_in[10];
  const float* Wv    = (const float*)d_in[11];
  const float* bv    = (const float*)d_in[12];
  const float* Wqg   = (const float*)d_in[13];
  const float* bqg   = (const float*)d_in[14];
  const float* Wkg   = (const float*)d_in[15];
  const float* bkg   = (const float*)d_in[16];
  const float* Wvg   = (const float*)d_in[17];
  const float* bvg   = (const float*)d_in[18];
  const float* Wo    = (const float*)d_in[19];
  const float* bo    = (const float*)d_in[20];
  const float* ln1s  = (const float*)d_in[21];
  const float* ln1b  = (const float*)d_in[22];
  const float* Wf1   = (const float*)d_in[23];
  const float* bf1   = (const float*)d_in[24];
  const float* Wf2   = (const float*)d_in[25];
  const float* bf2   = (const float*)d_in[26];
  const float* ln2s  = (const float*)d_in[27];
  const float* ln2b  = (const float*)d_in[28];
  const float* dw    = (const float*)d_in[29];
  const float* db    = (const float*)d_in[30];
  const float* ow    = (const float*)d_in[31];
  const float* ob    = (const float*)d_in[32];

  char* ws = (char*)d_ws;
  size_t off = 0;
  auto alloc = [&](size_t bytes)->char*{
    char* p = ws + off; off += (bytes + 255) & ~(size_t)255; return p;
  };
  float* h     = (float*)alloc((size_t)2048*768*4);
  bf16*  hb    = (bf16*) alloc((size_t)2048*768*2);
  float* h2    = (float*)alloc((size_t)2048*768*4);
  bf16*  h2b   = (bf16*) alloc((size_t)2048*768*2);
  bf16*  qkv   = (bf16*) alloc((size_t)2048*3840*2);
  bf16*  att   = (bf16*) alloc((size_t)2048*768*2);
  bf16*  f1    = (bf16*) alloc((size_t)2048*3072*2);
  bf16*  Vtb   = (bf16*) alloc((size_t)768*2048*2);    // V^T per layer [head*64+d][s]
  float* pf    = (float*)alloc((size_t)4*2048*768*4);  // 4 split-K partials
  bf16*  WcatT = (bf16*) alloc((size_t)12*5*768*768*2);
  bf16*  WoT   = (bf16*) alloc((size_t)12*768*768*2);
  bf16*  Wf1T  = (bf16*) alloc((size_t)12*768*3072*2);
  bf16*  Wf2T  = (bf16*) alloc((size_t)12*768*3072*2);
  float* bcat  = (float*)alloc((size_t)12*3840*4);

  prep_all<<<dim3(519,12),256,0,stream>>>(Wq, Wk, Wv, Wkg, Wvg, Wo, Wf1, Wf2,
                                          bq, bk, bv, bkg, bvg,
                                          WcatT, WoT, Wf1T, Wf2T, bcat);
  embed_ln<<<2048,256,0,stream>>>(ids, wemb, pemb, elns, elnb, h, hb);

  for (int l=0; l<12; l++) {
    const size_t oHH = (size_t)l*768*768;
    const size_t oH  = (size_t)l*768;
    const size_t oF  = (size_t)l*3072;
    const bf16* WcatT_l = WcatT + (size_t)l*5*768*768;
    const bf16* WoT_l   = WoT   + (size_t)l*768*768;
    const bf16* Wf1T_l  = Wf1T  + (size_t)l*768*3072;
    const bf16* Wf2T_l  = Wf2T  + (size_t)l*768*3072;
    const float* bcat_l = bcat  + (size_t)l*3840;

    gemm_bt<0,1,0,1,1><<<dim3(16,30),256,0,stream>>>(hb, WcatT_l, bcat_l, nullptr, qkv,
                                                     Vtb, 2048, 3840, 768);
    band_attn<<<dim3(8,12,5),256,0,stream>>>(qkv, Vtb, h, Wqg+oHH, bqg+oH,
                                             amask, gmask, att);
    gemm_bt<1,0,0,4,0><<<dim3(16,6,4),256,0,stream>>>(att, WoT_l, bo+oH, pf, nullptr,
                                                      nullptr, 2048, 768, 768);
    add_ln<<<2048,256,0,stream>>>(h, pf, ln1s+oH, ln1b+oH, h2, h2b);
    gemm_bt<0,1,1,1,0><<<dim3(16,24),256,0,stream>>>(h2b, Wf1T_l, bf1+oF, nullptr, f1,
                                                     nullptr, 2048, 3072, 768);
    gemm_bt<1,0,0,4,0><<<dim3(16,6,4),256,0,stream>>>(f1, Wf2T_l, bf2+oH, pf, nullptr,
                                                      nullptr, 2048, 768, 3072);
    add_ln<<<2048,256,0,stream>>>(h2, pf, ln2s+oH, ln2b+oH, h, hb);
  }

  head<<<1,768,0,stream>>>(h, dw, db, ow, ob, (float*)d_out);
}

// Round 12
// 2230.375 us; speedup vs baseline: 1.0061x; 1.0061x over previous
//
#include <hip/hip_runtime.h>
#include <hip/hip_bf16.h>

typedef __hip_bfloat16 bf16;
using bf16x8 = __attribute__((ext_vector_type(8))) short;
using f32x4  = __attribute__((ext_vector_type(4))) float;

#define kNEG 1.0e9f

__device__ __forceinline__ float b2f(bf16 x){ return __bfloat162float(x); }
__device__ __forceinline__ bf16  f2b(float x){ return __float2bfloat16(x); }

#define GLDS16(gp, lp) __builtin_amdgcn_global_load_lds( \
    (const __attribute__((address_space(1))) void*)(gp), \
    (__attribute__((address_space(3))) void*)(lp), 16, 0, 0)

__device__ __forceinline__ void unpack8(uint4 u, float* f){
  f[0]=__uint_as_float(u.x<<16); f[1]=__uint_as_float(u.x&0xffff0000u);
  f[2]=__uint_as_float(u.y<<16); f[3]=__uint_as_float(u.y&0xffff0000u);
  f[4]=__uint_as_float(u.z<<16); f[5]=__uint_as_float(u.z&0xffff0000u);
  f[6]=__uint_as_float(u.w<<16); f[7]=__uint_as_float(u.w&0xffff0000u);
}

// ---------------- embedding + LN ----------------
__global__ __launch_bounds__(256)
void embed_ln(const int* __restrict__ ids, const float* __restrict__ wemb,
              const float* __restrict__ pemb, const float* __restrict__ lns,
              const float* __restrict__ lnb, float* __restrict__ hout,
              bf16* __restrict__ hbout)
{
  const int row = blockIdx.x;
  const int tid = threadIdx.x;
  const int wave = tid >> 6, lane = tid & 63;
  const int id = ids[row];
  float x[3];
  #pragma unroll
  for (int p=0;p<3;p++){
    int i = tid + p*256;
    x[p] = wemb[(size_t)id*768 + i] + pemb[(size_t)row*768 + i];
  }
  float s1 = x[0]+x[1]+x[2];
  float s2 = x[0]*x[0]+x[1]*x[1]+x[2]*x[2];
  #pragma unroll
  for (int m=32;m>=1;m>>=1){ s1 += __shfl_xor(s1,m); s2 += __shfl_xor(s2,m); }
  __shared__ float red[8];
  if (lane==0){ red[wave]=s1; red[4+wave]=s2; }
  __syncthreads();
  s1 = red[0]+red[1]+red[2]+red[3];
  s2 = red[4]+red[5]+red[6]+red[7];
  float mu = s1*(1.0f/768.0f);
  float var = s2*(1.0f/768.0f) - mu*mu;
  float rs = rsqrtf(var + 1e-5f);
  #pragma unroll
  for (int p=0;p<3;p++){
    int i = tid + p*256;
    float y = (x[p]-mu)*rs*lns[i] + lnb[i];
    hout[(size_t)row*768+i] = y;
    hbout[(size_t)row*768+i] = f2b(y);
  }
}

// ---------------- residual add (four bf16 partials) + LN ----------------
__global__ __launch_bounds__(256)
void add_ln(const float* __restrict__ res, const bf16* __restrict__ pf,
            const float* __restrict__ lns, const float* __restrict__ lnb,
            float* __restrict__ hout, bf16* __restrict__ hbout)
{
  const size_t MN = (size_t)2048*768;
  const int row = blockIdx.x;
  const int tid = threadIdx.x;
  const int wave = tid >> 6, lane = tid & 63;
  float x[3];
  #pragma unroll
  for (int p=0;p<3;p++){
    int i = tid + p*256;
    size_t idx = (size_t)row*768+i;
    x[p] = res[idx] + ((b2f(pf[idx]) + b2f(pf[MN+idx]))
                     + (b2f(pf[2*MN+idx]) + b2f(pf[3*MN+idx])));
  }
  float s1 = x[0]+x[1]+x[2];
  float s2 = x[0]*x[0]+x[1]*x[1]+x[2]*x[2];
  #pragma unroll
  for (int m=32;m>=1;m>>=1){ s1 += __shfl_xor(s1,m); s2 += __shfl_xor(s2,m); }
  __shared__ float red[8];
  if (lane==0){ red[wave]=s1; red[4+wave]=s2; }
  __syncthreads();
  s1 = red[0]+red[1]+red[2]+red[3];
  s2 = red[4]+red[5]+red[6]+red[7];
  float mu = s1*(1.0f/768.0f);
  float var = s2*(1.0f/768.0f) - mu*mu;
  float rs = rsqrtf(var + 1e-5f);
  #pragma unroll
  for (int p=0;p<3;p++){
    int i = tid + p*256;
    float y = (x[p]-mu)*rs*lns[i] + lnb[i];
    hout[(size_t)row*768+i] = y;
    hbout[(size_t)row*768+i] = f2b(y);
  }
}

// ---------------- per-LAYER weight transpose -> swizzled BK-64 TILED layout ----------------
// One launch per layer (grid.x = 519): 12 small dispatches instead of 1 big one.
__global__ __launch_bounds__(256)
void prep_layer(const float* __restrict__ Wq, const float* __restrict__ Wk,
                const float* __restrict__ Wv, const float* __restrict__ Wkg,
                const float* __restrict__ Wvg, const float* __restrict__ Wo,
                const float* __restrict__ Wf1, const float* __restrict__ Wf2,
                const float* __restrict__ bq, const float* __restrict__ bk,
                const float* __restrict__ bv, const float* __restrict__ bkg,
                const float* __restrict__ bvg,
                bf16* __restrict__ WcatT, bf16* __restrict__ WoT,
                bf16* __restrict__ Wf1T, bf16* __restrict__ Wf2T,
                float* __restrict__ bcat, int l)
{
  const int b = blockIdx.x;
  const int tid = threadIdx.x;
  const size_t oHH = (size_t)l*768*768;
  const size_t oHF = (size_t)l*768*3072;
  const size_t oH  = (size_t)l*768;
  if (b >= 504) {
    int i = (b-504)*256 + tid;   // 0..3839
    int which = i / 768, j = i - which*768;
    float v;
    if      (which==0) v = bq[oH+j] * 0.125f;
    else if (which==1) v = bk[oH+j];
    else if (which==2) v = bv[oH+j];
    else if (which==3) v = bkg[oH+j];
    else               v = bvg[oH+j];
    bcat[(size_t)l*3840 + i] = v;
    return;
  }
  const float* src; bf16* dst; int N, KT64, p0, tk, k0, n0; float scale = 1.0f;
  if (b < 180) {
    int wsel = b/36, tile = b - wsel*36;
    int tkk = tile/3, tn = tile - tkk*3;
    if      (wsel==0){ src=Wq+oHH;  scale=0.125f; }
    else if (wsel==1){ src=Wk+oHH; }
    else if (wsel==2){ src=Wv+oHH; }
    else if (wsel==3){ src=Wkg+oHH; }
    else             { src=Wvg+oHH; }
    dst = WcatT + (size_t)l*5*768*768;
    N=768; KT64=12; k0=tkk*64; n0=tn*256; p0 = wsel*6 + tn*2; tk = tkk;
  } else if (b < 216) {
    int tile = b-180, tkk = tile/3, tn = tile - tkk*3;
    src = Wo+oHH; dst = WoT + (size_t)l*768*768;
    N=768; KT64=12; k0=tkk*64; n0=tn*256; p0 = tn*2; tk = tkk;
  } else if (b < 360) {
    int tile = b-216, tkk = tile/12, tn = tile - tkk*12;
    src = Wf1+oHF; dst = Wf1T + (size_t)l*768*3072;
    N=3072; KT64=12; k0=tkk*64; n0=tn*256; p0 = tn*2; tk = tkk;
  } else {
    int tile = b-360, tkk = tile/3, tn = tile - tkk*3;
    src = Wf2+oHF; dst = Wf2T + (size_t)l*768*3072;
    N=768; KT64=48; k0=tkk*64; n0=tn*256; p0 = tn*2; tk = tkk;
  }

  __shared__ bf16 t[64][264];
  const int wave = tid>>6, lane = tid&63;
  float4 v[16];
  #pragma unroll
  for (int i=0;i<16;i++){
    int r = i*4 + wave;
    v[i] = *(const float4*)&src[(size_t)(k0+r)*N + n0 + lane*4];
  }
  #pragma unroll
  for (int i=0;i<16;i++){
    int r = i*4 + wave;
    union { ushort4 u; bf16 h[4]; } pk;
    pk.h[0]=f2b(v[i].x*scale); pk.h[1]=f2b(v[i].y*scale);
    pk.h[2]=f2b(v[i].z*scale); pk.h[3]=f2b(v[i].w*scale);
    *(ushort4*)&t[r][lane*4] = pk.u;
  }
  __syncthreads();
  const int rr = tid>>1, half = tid&1;
  const int r7 = rr & 7;
  #pragma unroll
  for (int c=0;c<4;c++){
    const int pp = c>>1, tt = c&1;
    union { uint4 u[2]; bf16 h[16]; } pk;
    #pragma unroll
    for (int j=0;j<16;j++)
      pk.h[j] = t[tt*32 + half*16 + j][pp*128 + rr];
    bf16* base = dst + ((size_t)(p0+pp)*KT64 + tk)*8192 + rr*64;
    const int g0 = tt*4 + half*2;
    *(uint4*)(base + (((g0  ) ^ r7)<<3)) = pk.u[0];
    *(uint4*)(base + (((g0+1) ^ r7)<<3)) = pk.u[1];
  }
}

// ---------------- MFMA GEMM (BK=64, depth-2 counted-vmcnt, XOR-swizzled LDS) ----------------
// OUTF (split-K partial) now writes bf16 into pfb + z*M*N.
template<int OUTF, int OUTB, int GELU, int KSPLIT, int VT>
__global__ __launch_bounds__(256)
void gemm_bt(const bf16* __restrict__ A, const bf16* __restrict__ Bt,
             const float* __restrict__ bias,
             bf16* __restrict__ pfb, bf16* __restrict__ outb,
             bf16* __restrict__ vt,
             int M, int N, int K)
{
  __shared__ bf16 As[2][128*64];
  __shared__ bf16 Bs[2][128*64];
  const int tid  = threadIdx.x;
  const int lane = tid & 63;
  const int wave = tid >> 6;
  const int wm = wave >> 1, wn = wave & 1;
  const int gx = gridDim.x, nwg = gx*gridDim.y;
  const int w  = blockIdx.y*gx + blockIdx.x;
  const int cpx = nwg >> 3;
  const int sw = (w & 7)*cpx + (w >> 3);
  const int bm = sw % gx, bn = sw / gx;
  const int bz = (KSPLIT>1) ? blockIdx.z : 0;
  const int fr = lane & 15;
  const int fk = lane >> 4;
  const int x7 = fr & 7;
  const int Ks = K / KSPLIT;
  const int nt = Ks >> 6;
  const int kbeg = bz * Ks;
  const int KT64 = K >> 6;

  const bf16* pa[4];
  int ldsA[4];
  #pragma unroll
  for (int i=0;i<4;i++){
    int s = i*256 + tid;
    int row = s >> 3, k8l = s & 7;
    pa[i] = A + (size_t)(bm*128 + row)*K + kbeg + ((k8l ^ (row&7))<<3);
    ldsA[i] = s*8;
  }
  const bf16* pB = Bt + ((size_t)bn*KT64 + (kbeg>>6))*8192;

  f32x4 acc[4][4];
  const f32x4 zero = {0.f,0.f,0.f,0.f};
  #pragma unroll
  for (int i=0;i<4;i++)
    #pragma unroll
    for (int j=0;j<4;j++) acc[i][j] = zero;

  #pragma unroll
  for (int i=0;i<4;i++) GLDS16(pa[i], &As[0][ldsA[i]]);
  #pragma unroll
  for (int i=0;i<4;i++){ int o=(i*256+tid)*8; GLDS16(pB+o, &Bs[0][o]); }
  if (nt > 1) {
    #pragma unroll
    for (int i=0;i<4;i++) GLDS16(pa[i]+64, &As[1][ldsA[i]]);
    #pragma unroll
    for (int i=0;i<4;i++){ int o=(i*256+tid)*8; GLDS16(pB+8192+o, &Bs[1][o]); }
  }

  for (int t = 0; t < nt; ++t) {
    const int cur = t & 1;
    if (t < nt-1) asm volatile("s_waitcnt vmcnt(8)" ::: "memory");
    else          asm volatile("s_waitcnt vmcnt(0)" ::: "memory");
    __builtin_amdgcn_s_barrier();
    __builtin_amdgcn_sched_barrier(0);

    bf16x8 af[2][4], bfr[2][4];
    #pragma unroll
    for (int kk=0;kk<2;kk++){
      #pragma unroll
      for (int m=0;m<4;m++)
        af[kk][m] = *reinterpret_cast<const bf16x8*>(
            &As[cur][(wm*64 + m*16 + fr)*64 + ((((kk<<2)+fk) ^ x7)<<3)]);
      #pragma unroll
      for (int n=0;n<4;n++)
        bfr[kk][n] = *reinterpret_cast<const bf16x8*>(
            &Bs[cur][(wn*64 + n*16 + fr)*64 + ((((kk<<2)+fk) ^ x7)<<3)]);
    }
    __builtin_amdgcn_s_setprio(1);
    #pragma unroll
    for (int kk=0;kk<2;kk++)
      #pragma unroll
      for (int m=0;m<4;m++)
        #pragma unroll
        for (int n=0;n<4;n++)
          acc[m][n] = __builtin_amdgcn_mfma_f32_16x16x32_bf16(af[kk][m], bfr[kk][n], acc[m][n], 0,0,0);
    __builtin_amdgcn_s_setprio(0);

    __builtin_amdgcn_s_barrier();
    __builtin_amdgcn_sched_barrier(0);
    if (t+2 < nt) {
      #pragma unroll
      for (int i=0;i<4;i++) GLDS16(pa[i] + (size_t)(t+2)*64, &As[cur][ldsA[i]]);
      #pragma unroll
      for (int i=0;i<4;i++){ int o=(i*256+tid)*8;
        GLDS16(pB + (size_t)(t+2)*8192 + o, &Bs[cur][o]); }
    }
  }

  const int row0 = bm*128 + wm*64 + (lane>>4)*4;
  const int col0 = bn*128 + wn*64 + fr;
  bf16* pfz = OUTF ? (pfb + (size_t)bz*M*N) : nullptr;
  #pragma unroll
  for (int n=0;n<4;n++){
    const int col = col0 + n*16;
    const float bv = (bz==0) ? bias[col] : 0.f;
    #pragma unroll
    for (int m=0;m<4;m++){
      const int r0 = row0 + m*16;
      union { ushort4 u; bf16 h[4]; } pk;
      #pragma unroll
      for (int r=0;r<4;r++){
        float x = acc[m][n][r] + bv;
        if (GELU) x = 0.5f*x*(1.0f + erff(x*0.70710678118f));
        size_t idx = (size_t)(r0+r)*N + col;
        pk.h[r] = f2b(x);
        if (OUTF) pfz[idx] = pk.h[r];
        if (OUTB) outb[idx] = pk.h[r];
      }
      if (VT) {
        if (col >= 1536 && col < 2304)
          *(ushort4*)&vt[(size_t)(col-1536)*2048 + r0] = pk.u;
      }
    }
  }
}

// ---------------- band + global attention (merged launch) ----------------
// Band path uses max-free softmax: scores are bounded (|S| << 80) so
// exp(S)/sum(exp(S)) is exact; masked lanes get exp(-1e9)=0 exactly.
__global__ __launch_bounds__(256)
void band_attn(const bf16* __restrict__ qkv, const bf16* __restrict__ Vt,
               const float* __restrict__ h0, const float* __restrict__ Wqg,
               const float* __restrict__ bqg,
               const int* __restrict__ amask, const int* __restrict__ gmask,
               bf16* __restrict__ attn)
{
  const int c = blockIdx.x, n = blockIdx.y, rg = blockIdx.z;
  const int tid = threadIdx.x, wave = tid>>6, lane = tid&63;

  if (rg == 4) {
    if (c != 0) return;
    __shared__ float sg[2048];
    __shared__ float qh[64];
    __shared__ float redg[8];
    __shared__ float partg[4][64];
    {
      const int d = tid & 63;
      const int w = tid >> 6;
      const float* wp = Wqg + (size_t)(w*192)*768 + n*64 + d;
      float a = 0.f;
      #pragma unroll 8
      for (int k=0;k<192;k++) a += h0[w*192+k] * wp[(size_t)k*768];
      partg[w][d] = a;
    }
    __syncthreads();
    if (tid < 64)
      qh[tid] = (partg[0][tid]+partg[1][tid]+partg[2][tid]+partg[3][tid] + bqg[n*64+tid]) * 0.125f;
    __syncthreads();

    float smax = -3.0e38f;
    for (int p=0;p<8;p++){
      int s = p*256 + tid;
      const uint4* kr = (const uint4*)(qkv + (size_t)s*3840 + 2304 + n*64);
      float acc = 0.f;
      #pragma unroll
      for (int d8=0; d8<8; d8++){
        float f[8]; unpack8(kr[d8], f);
        #pragma unroll
        for (int e=0;e<8;e++) acc += f[e]*qh[d8*8+e];
      }
      if (amask[s] == 0) acc = -kNEG;
      sg[s] = acc;
      smax = fmaxf(smax, acc);
    }
    #pragma unroll
    for (int mk=32; mk>=1; mk>>=1) smax = fmaxf(smax, __shfl_xor(smax, mk));
    if (lane==0) redg[wave] = smax;
    __syncthreads();
    smax = fmaxf(fmaxf(redg[0],redg[1]),fmaxf(redg[2],redg[3]));
    float ssum = 0.f;
    for (int p=0;p<8;p++){
      int s = p*256 + tid;
      float e = __expf(sg[s]-smax);
      sg[s] = e;
      ssum += e;
    }
    #pragma unroll
    for (int mk=32; mk>=1; mk>>=1) ssum += __shfl_xor(ssum, mk);
    if (lane==0) redg[4+wave] = ssum;
    __syncthreads();
    float total = redg[4]+redg[5]+redg[6]+redg[7];
    __syncthreads();

    float o0=0.f,o1=0.f,o2=0.f,o3=0.f;
    const int base = wave*512;
    for (int s = base; s < base+512; s+=4){
      o0 += sg[s]   * b2f(qkv[(size_t)s*3840     + 3072 + n*64 + lane]);
      o1 += sg[s+1] * b2f(qkv[(size_t)(s+1)*3840 + 3072 + n*64 + lane]);
      o2 += sg[s+2] * b2f(qkv[(size_t)(s+2)*3840 + 3072 + n*64 + lane]);
      o3 += sg[s+3] * b2f(qkv[(size_t)(s+3)*3840 + 3072 + n*64 + lane]);
    }
    partg[wave][lane] = (o0+o1)+(o2+o3);
    __syncthreads();
    if (tid < 64) {
      float oo = (partg[0][tid]+partg[1][tid]+partg[2][tid]+partg[3][tid]) / total;
      attn[n*64+tid] = f2b(oo);
    }
    return;
  }

  // ---- band path ----
  const int fr = lane & 15, fk = lane >> 4;
  const int jj = tid >> 2, seg = tid & 3;

  __shared__ __attribute__((aligned(16))) bf16 q_s[64][72];
  __shared__ __attribute__((aligned(16))) bf16 k_s[2][64][72];
  __shared__ __attribute__((aligned(16))) bf16 vt_s[2][64][72];
  __shared__ __attribute__((aligned(16))) bf16 p_s[4][16][72];
  __shared__ int  okk_s[768];
  __shared__ float kv0[2][64];

  {
    const uint4* src = (const uint4*)(qkv + (size_t)(c*256 + rg*64 + jj)*3840 + n*64 + seg*16);
    *(uint4*)&q_s[jj][seg*16]   = src[0];
    *(uint4*)&q_s[jj][seg*16+8] = src[1];
  }
  #pragma unroll
  for (int p=0;p<3;p++){
    int j = tid + p*256;
    int kpos = c*256 + j - 256;
    int ok = 0;
    if (kpos >= 0 && kpos < 2048) ok = (amask[kpos] != 0) && (gmask[kpos] == 0);
    okk_s[j] = ok;
  }
  if (tid < 64)       kv0[0][tid]    = b2f(qkv[768  + n*64 + tid]);
  else if (tid < 128) kv0[1][tid-64] = b2f(qkv[1536 + n*64 + (tid-64)]);

  auto loadK = [&](int kt, uint4& a, uint4& b){
    int kpos = c*256 + kt*64 + jj - 256;
    int kq = kpos < 0 ? 0 : (kpos > 2047 ? 2047 : kpos);
    const uint4* ks = (const uint4*)(qkv + (size_t)kq*3840 + 768 + n*64 + seg*16);
    a = ks[0]; b = ks[1];
  };
  auto loadV = [&](int kt, uint4& a, uint4& b){
    int base = c*256 + kt*64 - 256;
    int sb = (base < 0 || base > 2048-64) ? 0 : base;
    const uint4* vs = (const uint4*)(Vt + (size_t)(n*64 + jj)*2048 + sb + seg*8);
    a = vs[0]; b = vs[4];
  };

  // clip to tiles with at least one in-range key
  const int kt_lo = (c==0) ? ((rg > 4) ? rg : 4) : rg;
  int kt_hi = rg+8 < 11 ? rg+8 : 11;
  const int clip = (2303 - c*256) >> 6;
  if (kt_hi > clip) kt_hi = clip;

  uint4 ka,kb,va,vb;
  loadK(kt_lo,ka,kb); loadV(kt_lo,va,vb);
  *(uint4*)&k_s[0][jj][seg*16]    = ka;
  *(uint4*)&k_s[0][jj][seg*16+8]  = kb;
  *(uint4*)&vt_s[0][jj][seg*8]    = va;
  *(uint4*)&vt_s[0][jj][seg*8+32] = vb;

  float lsum[4];
  f32x4 out[4];
  const f32x4 zero = {0.f,0.f,0.f,0.f};
  #pragma unroll
  for (int r=0;r<4;r++) lsum[r] = 0.f;
  #pragma unroll
  for (int dt=0;dt<4;dt++) out[dt] = zero;

  int cur = 0;
  for (int kt = kt_lo; kt <= kt_hi; kt++) {
    const bool pf = (kt < kt_hi);
    if (pf){ loadK(kt+1,ka,kb); loadV(kt+1,va,vb); }
    __syncthreads();

    f32x4 s[4];
    #pragma unroll
    for (int ct=0;ct<4;ct++) s[ct] = zero;
    __builtin_amdgcn_s_setprio(1);
    #pragma unroll
    for (int ks=0;ks<2;ks++){
      bf16x8 aq = *reinterpret_cast<const bf16x8*>(&q_s[wave*16 + fr][ks*32 + fk*8]);
      #pragma unroll
      for (int ct=0;ct<4;ct++){
        bf16x8 bk = *reinterpret_cast<const bf16x8*>(&k_s[cur][ct*16 + fr][ks*32 + fk*8]);
        s[ct] = __builtin_amdgcn_mfma_f32_16x16x32_bf16(aq, bk, s[ct], 0,0,0);
      }
    }
    __builtin_amdgcn_s_setprio(0);
    const int qbase = rg*64 + wave*16 + fk*4;
    // max-free softmax: P = exp(S) directly; masked -> exp(-1e9) = 0
    #pragma unroll
    for (int ct=0;ct<4;ct++){
      int j = kt*64 + ct*16 + fr;
      int okj = okk_s[j];
      #pragma unroll
      for (int r=0;r<4;r++){
        unsigned rel = (unsigned)(j - (qbase + r));
        float sv = (okj && rel <= 512u) ? s[ct][r] : -kNEG;
        float p = __expf(sv);
        lsum[r] += p;
        p_s[wave][fk*4 + r][ct*16 + fr] = f2b(p);
      }
    }
    __builtin_amdgcn_s_setprio(1);
    #pragma unroll
    for (int ks=0;ks<2;ks++){
      bf16x8 ap = *reinterpret_cast<const bf16x8*>(&p_s[wave][fr][ks*32 + fk*8]);
      #pragma unroll
      for (int dt=0;dt<4;dt++){
        bf16x8 bv = *reinterpret_cast<const bf16x8*>(&vt_s[cur][dt*16 + fr][ks*32 + fk*8]);
        out[dt] = __builtin_amdgcn_mfma_f32_16x16x32_bf16(ap, bv, out[dt], 0,0,0);
      }
    }
    __builtin_amdgcn_s_setprio(0);

    if (pf){
      *(uint4*)&k_s[cur^1][jj][seg*16]    = ka;
      *(uint4*)&k_s[cur^1][jj][seg*16+8]  = kb;
      *(uint4*)&vt_s[cur^1][jj][seg*8]    = va;
      *(uint4*)&vt_s[cur^1][jj][seg*8+32] = vb;
      cur ^= 1;
    }
  }

  // single end-of-loop row-sum reduce + global column + finalize
  const bool okg = (amask[0] != 0);
  #pragma unroll
  for (int r=0;r<4;r++){
    const int row16 = fk*4 + r;
    float ts = lsum[r];
    #pragma unroll
    for (int mk=8; mk>=1; mk>>=1) ts += __shfl_xor(ts, mk);
    float sp = 0.f;
    #pragma unroll
    for (int e=0;e<4;e++){
      int d = fr*4 + e;
      sp += b2f(q_s[wave*16 + row16][d]) * kv0[0][d];
    }
    #pragma unroll
    for (int mk=8; mk>=1; mk>>=1) sp += __shfl_xor(sp, mk);
    float pg = okg ? __expf(sp) : 0.f;
    float lf = ts + pg;
    const int srow = c*256 + rg*64 + wave*16 + row16;
    if (srow != 0) {
      #pragma unroll
      for (int dt=0;dt<4;dt++){
        int d = dt*16 + fr;
        float o = (out[dt][r] + pg*kv0[1][d]) / lf;
        attn[(size_t)srow*768 + n*64 + d] = f2b(o);
      }
    }
  }
}

// ---------------- head: tanh(h0 @ dw + db) @ ow + ob ----------------
__global__ __launch_bounds__(768)
void head(const float* __restrict__ h0, const float* __restrict__ dw,
          const float* __restrict__ db, const float* __restrict__ ow,
          const float* __restrict__ ob, float* __restrict__ out)
{
  __shared__ float y[768];
  const int tid = threadIdx.x;
  float acc = 0.f;
  #pragma unroll 8
  for (int k=0;k<768;k++) acc += h0[k]*dw[(size_t)k*768 + tid];
  y[tid] = tanhf(acc + db[tid]);
  __syncthreads();
  if (tid < 256) {
    float a = 0.f;
    #pragma unroll 8
    for (int k=0;k<768;k++) a += y[k]*ow[(size_t)k*256 + tid];
    out[tid] = a + ob[tid];
  }
}

// ---------------- host ----------------
extern "C" void kernel_launch(void* const* d_in, const int* in_sizes, int n_in,
                              void* d_out, int out_size, void* d_ws, size_t ws_size,
                              hipStream_t stream)
{
  const int*   ids   = (const int*)d_in[0];
  const int*   amask = (const int*)d_in[1];
  const int*   gmask = (const int*)d_in[2];
  const float* wemb  = (const float*)d_in[3];
  const float* pemb  = (const float*)d_in[4];
  const float* elns  = (const float*)d_in[5];
  const float* elnb  = (const float*)d_in[6];
  const float* Wq    = (const float*)d_in[7];
  const float* bq    = (const float*)d_in[8];
  const float* Wk    = (const float*)d_in[9];
  const float* bk    = (const float*)d_in[10];
  const float* Wv    = (const float*)d_in[11];
  const float* bv    = (const float*)d_in[12];
  const float* Wqg   = (const float*)d_in[13];
  const float* bqg   = (const float*)d_in[14];
  const float* Wkg   = (const float*)d_in[15];
  const float* bkg   = (const float*)d_in[16];
  const float* Wvg   = (const float*)d_in[17];
  const float* bvg   = (const float*)d_in[18];
  const float* Wo    = (const float*)d_in[19];
  const float* bo    = (const float*)d_in[20];
  const float* ln1s  = (const float*)d_in[21];
  const float* ln1b  = (const float*)d_in[22];
  const float* Wf1   = (const float*)d_in[23];
  const float* bf1   = (const float*)d_in[24];
  const float* Wf2   = (const float*)d_in[25];
  const float* bf2   = (const float*)d_in[26];
  const float* ln2s  = (const float*)d_in[27];
  const float* ln2b  = (const float*)d_in[28];
  const float* dw    = (const float*)d_in[29];
  const float* db    = (const float*)d_in[30];
  const float* ow    = (const float*)d_in[31];
  const float* ob    = (const float*)d_in[32];

  char* ws = (char*)d_ws;
  size_t off = 0;
  auto alloc = [&](size_t bytes)->char*{
    char* p = ws + off; off += (bytes + 255) & ~(size_t)255; return p;
  };
  float* h     = (float*)alloc((size_t)2048*768*4);
  bf16*  hb    = (bf16*) alloc((size_t)2048*768*2);
  float* h2    = (float*)alloc((size_t)2048*768*4);
  bf16*  h2b   = (bf16*) alloc((size_t)2048*768*2);
  bf16*  qkv   = (bf16*) alloc((size_t)2048*3840*2);
  bf16*  att   = (bf16*) alloc((size_t)2048*768*2);
  bf16*  f1    = (bf16*) alloc((size_t)2048*3072*2);
  bf16*  Vtb   = (bf16*) alloc((size_t)768*2048*2);    // V^T per layer [head*64+d][s]
  bf16*  pfb   = (bf16*) alloc((size_t)4*2048*768*2);  // 4 split-K partials (bf16)
  bf16*  WcatT = (bf16*) alloc((size_t)12*5*768*768*2);
  bf16*  WoT   = (bf16*) alloc((size_t)12*768*768*2);
  bf16*  Wf1T  = (bf16*) alloc((size_t)12*768*3072*2);
  bf16*  Wf2T  = (bf16*) alloc((size_t)12*768*3072*2);
  float* bcat  = (float*)alloc((size_t)12*3840*4);

  for (int l=0; l<12; l++)
    prep_layer<<<519,256,0,stream>>>(Wq, Wk, Wv, Wkg, Wvg, Wo, Wf1, Wf2,
                                     bq, bk, bv, bkg, bvg,
                                     WcatT, WoT, Wf1T, Wf2T, bcat, l);
  embed_ln<<<2048,256,0,stream>>>(ids, wemb, pemb, elns, elnb, h, hb);

  for (int l=0; l<12; l++) {
    const size_t oHH = (size_t)l*768*768;
    const size_t oH  = (size_t)l*768;
    const size_t oF  = (size_t)l*3072;
    const bf16* WcatT_l = WcatT + (size_t)l*5*768*768;
    const bf16* WoT_l   = WoT   + (size_t)l*768*768;
    const bf16* Wf1T_l  = Wf1T  + (size_t)l*768*3072;
    const bf16* Wf2T_l  = Wf2T  + (size_t)l*768*3072;
    const float* bcat_l = bcat  + (size_t)l*3840;

    gemm_bt<0,1,0,1,1><<<dim3(16,30),256,0,stream>>>(hb, WcatT_l, bcat_l, nullptr, qkv,
                                                     Vtb, 2048, 3840, 768);
    band_attn<<<dim3(8,12,5),256,0,stream>>>(qkv, Vtb, h, Wqg+oHH, bqg+oH,
                                             amask, gmask, att);
    gemm_bt<1,0,0,4,0><<<dim3(16,6,4),256,0,stream>>>(att, WoT_l, bo+oH, pfb, nullptr,
                                                      nullptr, 2048, 768, 768);
    add_ln<<<2048,256,0,stream>>>(h, pfb, ln1s+oH, ln1b+oH, h2, h2b);
    gemm_bt<0,1,1,1,0><<<dim3(16,24),256,0,stream>>>(h2b, Wf1T_l, bf1+oF, nullptr, f1,
                                                     nullptr, 2048, 3072, 768);
    gemm_bt<1,0,0,4,0><<<dim3(16,6,4),256,0,stream>>>(f1, Wf2T_l, bf2+oH, pfb, nullptr,
                                                      nullptr, 2048, 768, 3072);
    add_ln<<<2048,256,0,stream>>>(h2, pfb, ln2s+oH, ln2b+oH, h, hb);
  }

  head<<<1,768,0,stream>>>(h, dw, db, ow, ob, (float*)d_out);
}

// Round 13
// 2144.885 us; speedup vs baseline: 1.0462x; 1.0399x over previous
//
#include <hip/hip_runtime.h>
#include <hip/hip_bf16.h>

typedef __hip_bfloat16 bf16;
using bf16x8 = __attribute__((ext_vector_type(8))) short;
using f32x4  = __attribute__((ext_vector_type(4))) float;

#define kNEG 1.0e9f

__device__ __forceinline__ float b2f(bf16 x){ return __bfloat162float(x); }
__device__ __forceinline__ bf16  f2b(float x){ return __float2bfloat16(x); }

#define GLDS16(gp, lp) __builtin_amdgcn_global_load_lds( \
    (const __attribute__((address_space(1))) void*)(gp), \
    (__attribute__((address_space(3))) void*)(lp), 16, 0, 0)

__device__ __forceinline__ void unpack8(uint4 u, float* f){
  f[0]=__uint_as_float(u.x<<16); f[1]=__uint_as_float(u.x&0xffff0000u);
  f[2]=__uint_as_float(u.y<<16); f[3]=__uint_as_float(u.y&0xffff0000u);
  f[4]=__uint_as_float(u.z<<16); f[5]=__uint_as_float(u.z&0xffff0000u);
  f[6]=__uint_as_float(u.w<<16); f[7]=__uint_as_float(u.w&0xffff0000u);
}

// ---------------- embedding + LN ----------------
__global__ __launch_bounds__(256)
void embed_ln(const int* __restrict__ ids, const float* __restrict__ wemb,
              const float* __restrict__ pemb, const float* __restrict__ lns,
              const float* __restrict__ lnb, float* __restrict__ hout,
              bf16* __restrict__ hbout)
{
  const int row = blockIdx.x;
  const int tid = threadIdx.x;
  const int wave = tid >> 6, lane = tid & 63;
  const int id = ids[row];
  float x[3];
  #pragma unroll
  for (int p=0;p<3;p++){
    int i = tid + p*256;
    x[p] = wemb[(size_t)id*768 + i] + pemb[(size_t)row*768 + i];
  }
  float s1 = x[0]+x[1]+x[2];
  float s2 = x[0]*x[0]+x[1]*x[1]+x[2]*x[2];
  #pragma unroll
  for (int m=32;m>=1;m>>=1){ s1 += __shfl_xor(s1,m); s2 += __shfl_xor(s2,m); }
  __shared__ float red[8];
  if (lane==0){ red[wave]=s1; red[4+wave]=s2; }
  __syncthreads();
  s1 = red[0]+red[1]+red[2]+red[3];
  s2 = red[4]+red[5]+red[6]+red[7];
  float mu = s1*(1.0f/768.0f);
  float var = s2*(1.0f/768.0f) - mu*mu;
  float rs = rsqrtf(var + 1e-5f);
  #pragma unroll
  for (int p=0;p<3;p++){
    int i = tid + p*256;
    float y = (x[p]-mu)*rs*lns[i] + lnb[i];
    hout[(size_t)row*768+i] = y;
    hbout[(size_t)row*768+i] = f2b(y);
  }
}

// ---------------- residual add (four bf16 partials) + LN ----------------
__global__ __launch_bounds__(256)
void add_ln(const float* __restrict__ res, const bf16* __restrict__ pf,
            const float* __restrict__ lns, const float* __restrict__ lnb,
            float* __restrict__ hout, bf16* __restrict__ hbout)
{
  const size_t MN = (size_t)2048*768;
  const int row = blockIdx.x;
  const int tid = threadIdx.x;
  const int wave = tid >> 6, lane = tid & 63;
  float x[3];
  #pragma unroll
  for (int p=0;p<3;p++){
    int i = tid + p*256;
    size_t idx = (size_t)row*768+i;
    x[p] = res[idx] + ((b2f(pf[idx]) + b2f(pf[MN+idx]))
                     + (b2f(pf[2*MN+idx]) + b2f(pf[3*MN+idx])));
  }
  float s1 = x[0]+x[1]+x[2];
  float s2 = x[0]*x[0]+x[1]*x[1]+x[2]*x[2];
  #pragma unroll
  for (int m=32;m>=1;m>>=1){ s1 += __shfl_xor(s1,m); s2 += __shfl_xor(s2,m); }
  __shared__ float red[8];
  if (lane==0){ red[wave]=s1; red[4+wave]=s2; }
  __syncthreads();
  s1 = red[0]+red[1]+red[2]+red[3];
  s2 = red[4]+red[5]+red[6]+red[7];
  float mu = s1*(1.0f/768.0f);
  float var = s2*(1.0f/768.0f) - mu*mu;
  float rs = rsqrtf(var + 1e-5f);
  #pragma unroll
  for (int p=0;p<3;p++){
    int i = tid + p*256;
    float y = (x[p]-mu)*rs*lns[i] + lnb[i];
    hout[(size_t)row*768+i] = y;
    hbout[(size_t)row*768+i] = f2b(y);
  }
}

// ---------------- per-LAYER weight transpose -> swizzled BK-64 TILED layout ----------------
__global__ __launch_bounds__(256)
void prep_layer(const float* __restrict__ Wq, const float* __restrict__ Wk,
                const float* __restrict__ Wv, const float* __restrict__ Wkg,
                const float* __restrict__ Wvg, const float* __restrict__ Wo,
                const float* __restrict__ Wf1, const float* __restrict__ Wf2,
                const float* __restrict__ bq, const float* __restrict__ bk,
                const float* __restrict__ bv, const float* __restrict__ bkg,
                const float* __restrict__ bvg,
                bf16* __restrict__ WcatT, bf16* __restrict__ WoT,
                bf16* __restrict__ Wf1T, bf16* __restrict__ Wf2T,
                float* __restrict__ bcat, int l)
{
  const int b = blockIdx.x;
  const int tid = threadIdx.x;
  const size_t oHH = (size_t)l*768*768;
  const size_t oHF = (size_t)l*768*3072;
  const size_t oH  = (size_t)l*768;
  if (b >= 504) {
    int i = (b-504)*256 + tid;   // 0..3839
    int which = i / 768, j = i - which*768;
    float v;
    if      (which==0) v = bq[oH+j] * 0.125f;
    else if (which==1) v = bk[oH+j];
    else if (which==2) v = bv[oH+j];
    else if (which==3) v = bkg[oH+j];
    else               v = bvg[oH+j];
    bcat[(size_t)l*3840 + i] = v;
    return;
  }
  const float* src; bf16* dst; int N, KT64, p0, tk, k0, n0; float scale = 1.0f;
  if (b < 180) {
    int wsel = b/36, tile = b - wsel*36;
    int tkk = tile/3, tn = tile - tkk*3;
    if      (wsel==0){ src=Wq+oHH;  scale=0.125f; }
    else if (wsel==1){ src=Wk+oHH; }
    else if (wsel==2){ src=Wv+oHH; }
    else if (wsel==3){ src=Wkg+oHH; }
    else             { src=Wvg+oHH; }
    dst = WcatT + (size_t)l*5*768*768;
    N=768; KT64=12; k0=tkk*64; n0=tn*256; p0 = wsel*6 + tn*2; tk = tkk;
  } else if (b < 216) {
    int tile = b-180, tkk = tile/3, tn = tile - tkk*3;
    src = Wo+oHH; dst = WoT + (size_t)l*768*768;
    N=768; KT64=12; k0=tkk*64; n0=tn*256; p0 = tn*2; tk = tkk;
  } else if (b < 360) {
    int tile = b-216, tkk = tile/12, tn = tile - tkk*12;
    src = Wf1+oHF; dst = Wf1T + (size_t)l*768*3072;
    N=3072; KT64=12; k0=tkk*64; n0=tn*256; p0 = tn*2; tk = tkk;
  } else {
    int tile = b-360, tkk = tile/3, tn = tile - tkk*3;
    src = Wf2+oHF; dst = Wf2T + (size_t)l*768*3072;
    N=768; KT64=48; k0=tkk*64; n0=tn*256; p0 = tn*2; tk = tkk;
  }

  __shared__ bf16 t[64][264];
  const int wave = tid>>6, lane = tid&63;
  float4 v[16];
  #pragma unroll
  for (int i=0;i<16;i++){
    int r = i*4 + wave;
    v[i] = *(const float4*)&src[(size_t)(k0+r)*N + n0 + lane*4];
  }
  #pragma unroll
  for (int i=0;i<16;i++){
    int r = i*4 + wave;
    union { ushort4 u; bf16 h[4]; } pk;
    pk.h[0]=f2b(v[i].x*scale); pk.h[1]=f2b(v[i].y*scale);
    pk.h[2]=f2b(v[i].z*scale); pk.h[3]=f2b(v[i].w*scale);
    *(ushort4*)&t[r][lane*4] = pk.u;
  }
  __syncthreads();
  const int rr = tid>>1, half = tid&1;
  const int r7 = rr & 7;
  #pragma unroll
  for (int c=0;c<4;c++){
    const int pp = c>>1, tt = c&1;
    union { uint4 u[2]; bf16 h[16]; } pk;
    #pragma unroll
    for (int j=0;j<16;j++)
      pk.h[j] = t[tt*32 + half*16 + j][pp*128 + rr];
    bf16* base = dst + ((size_t)(p0+pp)*KT64 + tk)*8192 + rr*64;
    const int g0 = tt*4 + half*2;
    *(uint4*)(base + (((g0  ) ^ r7)<<3)) = pk.u[0];
    *(uint4*)(base + (((g0+1) ^ r7)<<3)) = pk.u[1];
  }
}

// ---------------- MFMA GEMM (BK=64, depth-2 counted-vmcnt, XOR-swizzled LDS) ----------------
template<int OUTF, int OUTB, int GELU, int KSPLIT, int VT>
__global__ __launch_bounds__(256)
void gemm_bt(const bf16* __restrict__ A, const bf16* __restrict__ Bt,
             const float* __restrict__ bias,
             bf16* __restrict__ pfb, bf16* __restrict__ outb,
             bf16* __restrict__ vt,
             int M, int N, int K)
{
  __shared__ bf16 As[2][128*64];
  __shared__ bf16 Bs[2][128*64];
  const int tid  = threadIdx.x;
  const int lane = tid & 63;
  const int wave = tid >> 6;
  const int wm = wave >> 1, wn = wave & 1;
  const int gx = gridDim.x, nwg = gx*gridDim.y;
  const int w  = blockIdx.y*gx + blockIdx.x;
  const int cpx = nwg >> 3;
  const int sw = (w & 7)*cpx + (w >> 3);
  const int bm = sw % gx, bn = sw / gx;
  const int bz = (KSPLIT>1) ? blockIdx.z : 0;
  const int fr = lane & 15;
  const int fk = lane >> 4;
  const int x7 = fr & 7;
  const int Ks = K / KSPLIT;
  const int nt = Ks >> 6;
  const int kbeg = bz * Ks;
  const int KT64 = K >> 6;

  const bf16* pa[4];
  int ldsA[4];
  #pragma unroll
  for (int i=0;i<4;i++){
    int s = i*256 + tid;
    int row = s >> 3, k8l = s & 7;
    pa[i] = A + (size_t)(bm*128 + row)*K + kbeg + ((k8l ^ (row&7))<<3);
    ldsA[i] = s*8;
  }
  const bf16* pB = Bt + ((size_t)bn*KT64 + (kbeg>>6))*8192;

  f32x4 acc[4][4];
  const f32x4 zero = {0.f,0.f,0.f,0.f};
  #pragma unroll
  for (int i=0;i<4;i++)
    #pragma unroll
    for (int j=0;j<4;j++) acc[i][j] = zero;

  #pragma unroll
  for (int i=0;i<4;i++) GLDS16(pa[i], &As[0][ldsA[i]]);
  #pragma unroll
  for (int i=0;i<4;i++){ int o=(i*256+tid)*8; GLDS16(pB+o, &Bs[0][o]); }
  if (nt > 1) {
    #pragma unroll
    for (int i=0;i<4;i++) GLDS16(pa[i]+64, &As[1][ldsA[i]]);
    #pragma unroll
    for (int i=0;i<4;i++){ int o=(i*256+tid)*8; GLDS16(pB+8192+o, &Bs[1][o]); }
  }

  for (int t = 0; t < nt; ++t) {
    const int cur = t & 1;
    if (t < nt-1) asm volatile("s_waitcnt vmcnt(8)" ::: "memory");
    else          asm volatile("s_waitcnt vmcnt(0)" ::: "memory");
    __builtin_amdgcn_s_barrier();
    __builtin_amdgcn_sched_barrier(0);

    bf16x8 af[2][4], bfr[2][4];
    #pragma unroll
    for (int kk=0;kk<2;kk++){
      #pragma unroll
      for (int m=0;m<4;m++)
        af[kk][m] = *reinterpret_cast<const bf16x8*>(
            &As[cur][(wm*64 + m*16 + fr)*64 + ((((kk<<2)+fk) ^ x7)<<3)]);
      #pragma unroll
      for (int n=0;n<4;n++)
        bfr[kk][n] = *reinterpret_cast<const bf16x8*>(
            &Bs[cur][(wn*64 + n*16 + fr)*64 + ((((kk<<2)+fk) ^ x7)<<3)]);
    }
    __builtin_amdgcn_s_setprio(1);
    #pragma unroll
    for (int kk=0;kk<2;kk++)
      #pragma unroll
      for (int m=0;m<4;m++)
        #pragma unroll
        for (int n=0;n<4;n++)
          acc[m][n] = __builtin_amdgcn_mfma_f32_16x16x32_bf16(af[kk][m], bfr[kk][n], acc[m][n], 0,0,0);
    __builtin_amdgcn_s_setprio(0);

    __builtin_amdgcn_s_barrier();
    __builtin_amdgcn_sched_barrier(0);
    if (t+2 < nt) {
      #pragma unroll
      for (int i=0;i<4;i++) GLDS16(pa[i] + (size_t)(t+2)*64, &As[cur][ldsA[i]]);
      #pragma unroll
      for (int i=0;i<4;i++){ int o=(i*256+tid)*8;
        GLDS16(pB + (size_t)(t+2)*8192 + o, &Bs[cur][o]); }
    }
  }

  const int row0 = bm*128 + wm*64 + (lane>>4)*4;
  const int col0 = bn*128 + wn*64 + fr;
  bf16* pfz = OUTF ? (pfb + (size_t)bz*M*N) : nullptr;
  #pragma unroll
  for (int n=0;n<4;n++){
    const int col = col0 + n*16;
    const float bv = (bz==0) ? bias[col] : 0.f;
    #pragma unroll
    for (int m=0;m<4;m++){
      const int r0 = row0 + m*16;
      union { ushort4 u; bf16 h[4]; } pk;
      #pragma unroll
      for (int r=0;r<4;r++){
        float x = acc[m][n][r] + bv;
        if (GELU) x = 0.5f*x*(1.0f + erff(x*0.70710678118f));
        size_t idx = (size_t)(r0+r)*N + col;
        pk.h[r] = f2b(x);
        if (OUTF) pfz[idx] = pk.h[r];
        if (OUTB) outb[idx] = pk.h[r];
      }
      if (VT) {
        if (col >= 1536 && col < 2304)
          *(ushort4*)&vt[(size_t)(col-1536)*2048 + r0] = pk.u;
      }
    }
  }
}

// ---------------- band + global attention (merged launch) ----------------
__global__ __launch_bounds__(256)
void band_attn(const bf16* __restrict__ qkv, const bf16* __restrict__ Vt,
               const float* __restrict__ h0, const float* __restrict__ Wqg,
               const float* __restrict__ bqg,
               const int* __restrict__ amask, const int* __restrict__ gmask,
               bf16* __restrict__ attn)
{
  const int c = blockIdx.x, n = blockIdx.y, rg = blockIdx.z;
  const int tid = threadIdx.x, wave = tid>>6, lane = tid&63;

  if (rg == 4) {
    if (c != 0) return;
    __shared__ float sg[2048];
    __shared__ float qh[64];
    __shared__ float redg[8];
    __shared__ float partg[4][64];
    {
      const int d = tid & 63;
      const int w = tid >> 6;
      const float* wp = Wqg + (size_t)(w*192)*768 + n*64 + d;
      float a = 0.f;
      #pragma unroll 8
      for (int k=0;k<192;k++) a += h0[w*192+k] * wp[(size_t)k*768];
      partg[w][d] = a;
    }
    __syncthreads();
    if (tid < 64)
      qh[tid] = (partg[0][tid]+partg[1][tid]+partg[2][tid]+partg[3][tid] + bqg[n*64+tid]) * 0.125f;
    __syncthreads();

    float smax = -3.0e38f;
    for (int p=0;p<8;p++){
      int s = p*256 + tid;
      const uint4* kr = (const uint4*)(qkv + (size_t)s*3840 + 2304 + n*64);
      float acc = 0.f;
      #pragma unroll
      for (int d8=0; d8<8; d8++){
        float f[8]; unpack8(kr[d8], f);
        #pragma unroll
        for (int e=0;e<8;e++) acc += f[e]*qh[d8*8+e];
      }
      if (amask[s] == 0) acc = -kNEG;
      sg[s] = acc;
      smax = fmaxf(smax, acc);
    }
    #pragma unroll
    for (int mk=32; mk>=1; mk>>=1) smax = fmaxf(smax, __shfl_xor(smax, mk));
    if (lane==0) redg[wave] = smax;
    __syncthreads();
    smax = fmaxf(fmaxf(redg[0],redg[1]),fmaxf(redg[2],redg[3]));
    float ssum = 0.f;
    for (int p=0;p<8;p++){
      int s = p*256 + tid;
      float e = __expf(sg[s]-smax);
      sg[s] = e;
      ssum += e;
    }
    #pragma unroll
    for (int mk=32; mk>=1; mk>>=1) ssum += __shfl_xor(ssum, mk);
    if (lane==0) redg[4+wave] = ssum;
    __syncthreads();
    float total = redg[4]+redg[5]+redg[6]+redg[7];
    __syncthreads();

    float o0=0.f,o1=0.f,o2=0.f,o3=0.f;
    const int base = wave*512;
    for (int s = base; s < base+512; s+=4){
      o0 += sg[s]   * b2f(qkv[(size_t)s*3840     + 3072 + n*64 + lane]);
      o1 += sg[s+1] * b2f(qkv[(size_t)(s+1)*3840 + 3072 + n*64 + lane]);
      o2 += sg[s+2] * b2f(qkv[(size_t)(s+2)*3840 + 3072 + n*64 + lane]);
      o3 += sg[s+3] * b2f(qkv[(size_t)(s+3)*3840 + 3072 + n*64 + lane]);
    }
    partg[wave][lane] = (o0+o1)+(o2+o3);
    __syncthreads();
    if (tid < 64) {
      float oo = (partg[0][tid]+partg[1][tid]+partg[2][tid]+partg[3][tid]) / total;
      attn[n*64+tid] = f2b(oo);
    }
    return;
  }

  // ---- band path ----
  const int fr = lane & 15, fk = lane >> 4;
  const int jj = tid >> 2, seg = tid & 3;

  __shared__ __attribute__((aligned(16))) bf16 q_s[64][72];
  __shared__ __attribute__((aligned(16))) bf16 k_s[2][64][72];
  __shared__ __attribute__((aligned(16))) bf16 vt_s[2][64][72];
  __shared__ __attribute__((aligned(16))) bf16 p_s[4][16][72];
  __shared__ int  okk_s[768];
  __shared__ float kv0[2][64];

  {
    const uint4* src = (const uint4*)(qkv + (size_t)(c*256 + rg*64 + jj)*3840 + n*64 + seg*16);
    *(uint4*)&q_s[jj][seg*16]   = src[0];
    *(uint4*)&q_s[jj][seg*16+8] = src[1];
  }
  #pragma unroll
  for (int p=0;p<3;p++){
    int j = tid + p*256;
    int kpos = c*256 + j - 256;
    int ok = 0;
    if (kpos >= 0 && kpos < 2048) ok = (amask[kpos] != 0) && (gmask[kpos] == 0);
    okk_s[j] = ok;
  }
  if (tid < 64)       kv0[0][tid]    = b2f(qkv[768  + n*64 + tid]);
  else if (tid < 128) kv0[1][tid-64] = b2f(qkv[1536 + n*64 + (tid-64)]);

  auto loadK = [&](int kt, uint4& a, uint4& b){
    int kpos = c*256 + kt*64 + jj - 256;
    int kq = kpos < 0 ? 0 : (kpos > 2047 ? 2047 : kpos);
    const uint4* ks = (const uint4*)(qkv + (size_t)kq*3840 + 768 + n*64 + seg*16);
    a = ks[0]; b = ks[1];
  };
  auto loadV = [&](int kt, uint4& a, uint4& b){
    int base = c*256 + kt*64 - 256;
    int sb = (base < 0 || base > 2048-64) ? 0 : base;
    const uint4* vs = (const uint4*)(Vt + (size_t)(n*64 + jj)*2048 + sb + seg*8);
    a = vs[0]; b = vs[4];
  };

  // clip to tiles with at least one in-range key
  const int kt_lo = (c==0) ? ((rg > 4) ? rg : 4) : rg;
  int kt_hi = rg+8 < 11 ? rg+8 : 11;
  const int clip = (2303 - c*256) >> 6;
  if (kt_hi > clip) kt_hi = clip;

  uint4 ka,kb,va,vb;
  loadK(kt_lo,ka,kb); loadV(kt_lo,va,vb);
  *(uint4*)&k_s[0][jj][seg*16]    = ka;
  *(uint4*)&k_s[0][jj][seg*16+8]  = kb;
  *(uint4*)&vt_s[0][jj][seg*8]    = va;
  *(uint4*)&vt_s[0][jj][seg*8+32] = vb;

  float lsum[4];
  f32x4 out[4];
  const f32x4 zero = {0.f,0.f,0.f,0.f};
  #pragma unroll
  for (int r=0;r<4;r++) lsum[r] = 0.f;
  #pragma unroll
  for (int dt=0;dt<4;dt++) out[dt] = zero;

  int cur = 0;
  for (int kt = kt_lo; kt <= kt_hi; kt++) {
    const bool pf = (kt < kt_hi);
    if (pf){ loadK(kt+1,ka,kb); loadV(kt+1,va,vb); }
    __syncthreads();

    f32x4 s[4];
    #pragma unroll
    for (int ct=0;ct<4;ct++) s[ct] = zero;
    __builtin_amdgcn_s_setprio(1);
    #pragma unroll
    for (int ks=0;ks<2;ks++){
      bf16x8 aq = *reinterpret_cast<const bf16x8*>(&q_s[wave*16 + fr][ks*32 + fk*8]);
      #pragma unroll
      for (int ct=0;ct<4;ct++){
        bf16x8 bk = *reinterpret_cast<const bf16x8*>(&k_s[cur][ct*16 + fr][ks*32 + fk*8]);
        s[ct] = __builtin_amdgcn_mfma_f32_16x16x32_bf16(aq, bk, s[ct], 0,0,0);
      }
    }
    __builtin_amdgcn_s_setprio(0);
    const int qbase = rg*64 + wave*16 + fk*4;
    // max-free softmax: P = exp(S) directly; masked -> exp(-1e9) = 0
    #pragma unroll
    for (int ct=0;ct<4;ct++){
      int j = kt*64 + ct*16 + fr;
      int okj = okk_s[j];
      #pragma unroll
      for (int r=0;r<4;r++){
        unsigned rel = (unsigned)(j - (qbase + r));
        float sv = (okj && rel <= 512u) ? s[ct][r] : -kNEG;
        float p = __expf(sv);
        lsum[r] += p;
        p_s[wave][fk*4 + r][ct*16 + fr] = f2b(p);
      }
    }
    __builtin_amdgcn_s_setprio(1);
    #pragma unroll
    for (int ks=0;ks<2;ks++){
      bf16x8 ap = *reinterpret_cast<const bf16x8*>(&p_s[wave][fr][ks*32 + fk*8]);
      #pragma unroll
      for (int dt=0;dt<4;dt++){
        bf16x8 bv = *reinterpret_cast<const bf16x8*>(&vt_s[cur][dt*16 + fr][ks*32 + fk*8]);
        out[dt] = __builtin_amdgcn_mfma_f32_16x16x32_bf16(ap, bv, out[dt], 0,0,0);
      }
    }
    __builtin_amdgcn_s_setprio(0);

    if (pf){
      *(uint4*)&k_s[cur^1][jj][seg*16]    = ka;
      *(uint4*)&k_s[cur^1][jj][seg*16+8]  = kb;
      *(uint4*)&vt_s[cur^1][jj][seg*8]    = va;
      *(uint4*)&vt_s[cur^1][jj][seg*8+32] = vb;
      cur ^= 1;
    }
  }

  // single end-of-loop row-sum reduce + global column + finalize
  const bool okg = (amask[0] != 0);
  #pragma unroll
  for (int r=0;r<4;r++){
    const int row16 = fk*4 + r;
    float ts = lsum[r];
    #pragma unroll
    for (int mk=8; mk>=1; mk>>=1) ts += __shfl_xor(ts, mk);
    float sp = 0.f;
    #pragma unroll
    for (int e=0;e<4;e++){
      int d = fr*4 + e;
      sp += b2f(q_s[wave*16 + row16][d]) * kv0[0][d];
    }
    #pragma unroll
    for (int mk=8; mk>=1; mk>>=1) sp += __shfl_xor(sp, mk);
    float pg = okg ? __expf(sp) : 0.f;
    float lf = ts + pg;
    const int srow = c*256 + rg*64 + wave*16 + row16;
    if (srow != 0) {
      #pragma unroll
      for (int dt=0;dt<4;dt++){
        int d = dt*16 + fr;
        float o = (out[dt][r] + pg*kv0[1][d]) / lf;
        attn[(size_t)srow*768 + n*64 + d] = f2b(o);
      }
    }
  }
}

// ---------------- head, parallelized: 4 small kernels ----------------
// p1: pd[z*768+col] = sum_{k in z-slice(96)} h0[k]*dw[k*768+col], grid (3,8)
__global__ __launch_bounds__(256)
void head_p1(const float* __restrict__ h0, const float* __restrict__ dw,
             float* __restrict__ pd)
{
  const int col = blockIdx.x*256 + threadIdx.x;
  const int z = blockIdx.y;
  const int k0 = z*96;
  float acc = 0.f;
  #pragma unroll 8
  for (int k=0;k<96;k++) acc += h0[k0+k]*dw[(size_t)(k0+k)*768 + col];
  pd[z*768 + col] = acc;
}

// y: y[col] = tanh(sum_z pd + db), grid 3
__global__ __launch_bounds__(256)
void head_y(const float* __restrict__ pd, const float* __restrict__ db,
            float* __restrict__ yv)
{
  const int col = blockIdx.x*256 + threadIdx.x;
  float a = 0.f;
  #pragma unroll
  for (int z=0;z<8;z++) a += pd[z*768 + col];
  yv[col] = tanhf(a + db[col]);
}

// p2: po[z*256+col] = sum_{k in z-slice(96)} y[k]*ow[k*256+col], grid 8
__global__ __launch_bounds__(256)
void head_p2(const float* __restrict__ yv, const float* __restrict__ ow,
             float* __restrict__ po)
{
  const int col = threadIdx.x;
  const int z = blockIdx.x;
  const int k0 = z*96;
  float acc = 0.f;
  #pragma unroll 8
  for (int k=0;k<96;k++) acc += yv[k0+k]*ow[(size_t)(k0+k)*256 + col];
  po[z*256 + col] = acc;
}

// final: out[col] = sum_z po + ob, grid 1
__global__ __launch_bounds__(256)
void head_fin(const float* __restrict__ po, const float* __restrict__ ob,
              float* __restrict__ out)
{
  const int col = threadIdx.x;
  float a = 0.f;
  #pragma unroll
  for (int z=0;z<8;z++) a += po[z*256 + col];
  out[col] = a + ob[col];
}

// ---------------- host ----------------
extern "C" void kernel_launch(void* const* d_in, const int* in_sizes, int n_in,
                              void* d_out, int out_size, void* d_ws, size_t ws_size,
                              hipStream_t stream)
{
  const int*   ids   = (const int*)d_in[0];
  const int*   amask = (const int*)d_in[1];
  const int*   gmask = (const int*)d_in[2];
  const float* wemb  = (const float*)d_in[3];
  const float* pemb  = (const float*)d_in[4];
  const float* elns  = (const float*)d_in[5];
  const float* elnb  = (const float*)d_in[6];
  const float* Wq    = (const float*)d_in[7];
  const float* bq    = (const float*)d_in[8];
  const float* Wk    = (const float*)d_in[9];
  const float* bk    = (const float*)d_in[10];
  const float* Wv    = (const float*)d_in[11];
  const float* bv    = (const float*)d_in[12];
  const float* Wqg   = (const float*)d_in[13];
  const float* bqg   = (const float*)d_in[14];
  const float* Wkg   = (const float*)d_in[15];
  const float* bkg   = (const float*)d_in[16];
  const float* Wvg   = (const float*)d_in[17];
  const float* bvg   = (const float*)d_in[18];
  const float* Wo    = (const float*)d_in[19];
  const float* bo    = (const float*)d_in[20];
  const float* ln1s  = (const float*)d_in[21];
  const float* ln1b  = (const float*)d_in[22];
  const float* Wf1   = (const float*)d_in[23];
  const float* bf1   = (const float*)d_in[24];
  const float* Wf2   = (const float*)d_in[25];
  const float* bf2   = (const float*)d_in[26];
  const float* ln2s  = (const float*)d_in[27];
  const float* ln2b  = (const float*)d_in[28];
  const float* dw    = (const float*)d_in[29];
  const float* db    = (const float*)d_in[30];
  const float* ow    = (const float*)d_in[31];
  const float* ob    = (const float*)d_in[32];

  char* ws = (char*)d_ws;
  size_t off = 0;
  auto alloc = [&](size_t bytes)->char*{
    char* p = ws + off; off += (bytes + 255) & ~(size_t)255; return p;
  };
  float* h     = (float*)alloc((size_t)2048*768*4);
  bf16*  hb    = (bf16*) alloc((size_t)2048*768*2);
  float* h2    = (float*)alloc((size_t)2048*768*4);
  bf16*  h2b   = (bf16*) alloc((size_t)2048*768*2);
  bf16*  qkv   = (bf16*) alloc((size_t)2048*3840*2);
  bf16*  att   = (bf16*) alloc((size_t)2048*768*2);
  bf16*  f1    = (bf16*) alloc((size_t)2048*3072*2);
  bf16*  Vtb   = (bf16*) alloc((size_t)768*2048*2);    // V^T per layer [head*64+d][s]
  bf16*  pfb   = (bf16*) alloc((size_t)4*2048*768*2);  // 4 split-K partials (bf16)
  bf16*  WcatT = (bf16*) alloc((size_t)12*5*768*768*2);
  bf16*  WoT   = (bf16*) alloc((size_t)12*768*768*2);
  bf16*  Wf1T  = (bf16*) alloc((size_t)12*768*3072*2);
  bf16*  Wf2T  = (bf16*) alloc((size_t)12*768*3072*2);
  float* bcat  = (float*)alloc((size_t)12*3840*4);
  float* pd    = (float*)alloc((size_t)8*768*4);
  float* yv    = (float*)alloc((size_t)768*4);
  float* po    = (float*)alloc((size_t)8*256*4);

  for (int l=0; l<12; l++)
    prep_layer<<<519,256,0,stream>>>(Wq, Wk, Wv, Wkg, Wvg, Wo, Wf1, Wf2,
                                     bq, bk, bv, bkg, bvg,
                                     WcatT, WoT, Wf1T, Wf2T, bcat, l);
  embed_ln<<<2048,256,0,stream>>>(ids, wemb, pemb, elns, elnb, h, hb);

  for (int l=0; l<12; l++) {
    const size_t oHH = (size_t)l*768*768;
    const size_t oH  = (size_t)l*768;
    const size_t oF  = (size_t)l*3072;
    const bf16* WcatT_l = WcatT + (size_t)l*5*768*768;
    const bf16* WoT_l   = WoT   + (size_t)l*768*768;
    const bf16* Wf1T_l  = Wf1T  + (size_t)l*768*3072;
    const bf16* Wf2T_l  = Wf2T  + (size_t)l*768*3072;
    const float* bcat_l = bcat  + (size_t)l*3840;

    gemm_bt<0,1,0,1,1><<<dim3(16,30),256,0,stream>>>(hb, WcatT_l, bcat_l, nullptr, qkv,
                                                     Vtb, 2048, 3840, 768);
    band_attn<<<dim3(8,12,5),256,0,stream>>>(qkv, Vtb, h, Wqg+oHH, bqg+oH,
                                             amask, gmask, att);
    gemm_bt<1,0,0,4,0><<<dim3(16,6,4),256,0,stream>>>(att, WoT_l, bo+oH, pfb, nullptr,
                                                      nullptr, 2048, 768, 768);
    add_ln<<<2048,256,0,stream>>>(h, pfb, ln1s+oH, ln1b+oH, h2, h2b);
    gemm_bt<0,1,1,1,0><<<dim3(16,24),256,0,stream>>>(h2b, Wf1T_l, bf1+oF, nullptr, f1,
                                                     nullptr, 2048, 3072, 768);
    gemm_bt<1,0,0,4,0><<<dim3(16,6,4),256,0,stream>>>(f1, Wf2T_l, bf2+oH, pfb, nullptr,
                                                      nullptr, 2048, 768, 3072);
    add_ln<<<2048,256,0,stream>>>(h2, pfb, ln2s+oH, ln2b+oH, h, hb);
  }

  head_p1<<<dim3(3,8),256,0,stream>>>(h, dw, pd);
  head_y<<<3,256,0,stream>>>(pd, db, yv);
  head_p2<<<8,256,0,stream>>>(yv, ow, po);
  head_fin<<<1,256,0,stream>>>(po, ob, (float*)d_out);
}

// Round 14
// 2136.766 us; speedup vs baseline: 1.0502x; 1.0038x over previous
//
#include <hip/hip_runtime.h>
#include <hip/hip_bf16.h>

typedef __hip_bfloat16 bf16;
using bf16x8 = __attribute__((ext_vector_type(8))) short;
using f32x4  = __attribute__((ext_vector_type(4))) float;

#define kNEG 1.0e9f

__device__ __forceinline__ float b2f(bf16 x){ return __bfloat162float(x); }
__device__ __forceinline__ bf16  f2b(float x){ return __float2bfloat16(x); }
__device__ __forceinline__ float us2f(unsigned short u){ return __uint_as_float(((unsigned)u)<<16); }

#define GLDS16(gp, lp) __builtin_amdgcn_global_load_lds( \
    (const __attribute__((address_space(1))) void*)(gp), \
    (__attribute__((address_space(3))) void*)(lp), 16, 0, 0)

__device__ __forceinline__ void unpack8(uint4 u, float* f){
  f[0]=__uint_as_float(u.x<<16); f[1]=__uint_as_float(u.x&0xffff0000u);
  f[2]=__uint_as_float(u.y<<16); f[3]=__uint_as_float(u.y&0xffff0000u);
  f[4]=__uint_as_float(u.z<<16); f[5]=__uint_as_float(u.z&0xffff0000u);
  f[6]=__uint_as_float(u.w<<16); f[7]=__uint_as_float(u.w&0xffff0000u);
}

// ---------------- embedding + LN (vectorized, 192 threads/row) ----------------
__global__ __launch_bounds__(192)
void embed_ln(const int* __restrict__ ids, const float* __restrict__ wemb,
              const float* __restrict__ pemb, const float* __restrict__ lns,
              const float* __restrict__ lnb, float* __restrict__ hout,
              bf16* __restrict__ hbout)
{
  const int row = blockIdx.x;
  const int tid = threadIdx.x;           // 0..191
  const int wave = tid >> 6, lane = tid & 63;
  const int id = ids[row];
  const int i0 = tid*4;
  float4 a = *(const float4*)&wemb[(size_t)id*768 + i0];
  float4 b = *(const float4*)&pemb[(size_t)row*768 + i0];
  float4 x = make_float4(a.x+b.x, a.y+b.y, a.z+b.z, a.w+b.w);
  float s1 = x.x+x.y+x.z+x.w;
  float s2 = x.x*x.x+x.y*x.y+x.z*x.z+x.w*x.w;
  #pragma unroll
  for (int m=32;m>=1;m>>=1){ s1 += __shfl_xor(s1,m); s2 += __shfl_xor(s2,m); }
  __shared__ float red[6];
  if (lane==0){ red[wave]=s1; red[3+wave]=s2; }
  __syncthreads();
  s1 = red[0]+red[1]+red[2];
  s2 = red[3]+red[4]+red[5];
  float mu = s1*(1.0f/768.0f);
  float var = s2*(1.0f/768.0f) - mu*mu;
  float rs = rsqrtf(var + 1e-5f);
  float4 sc = *(const float4*)&lns[i0];
  float4 bi = *(const float4*)&lnb[i0];
  float4 y = make_float4((x.x-mu)*rs*sc.x + bi.x, (x.y-mu)*rs*sc.y + bi.y,
                         (x.z-mu)*rs*sc.z + bi.z, (x.w-mu)*rs*sc.w + bi.w);
  *(float4*)&hout[(size_t)row*768 + i0] = y;
  union { ushort4 u; bf16 h[4]; } pk;
  pk.h[0]=f2b(y.x); pk.h[1]=f2b(y.y); pk.h[2]=f2b(y.z); pk.h[3]=f2b(y.w);
  *(ushort4*)&hbout[(size_t)row*768 + i0] = pk.u;
}

// ---------------- residual add (NP bf16 partials) + LN (vectorized) ----------------
template<int NP>
__global__ __launch_bounds__(192)
void add_ln(const float* __restrict__ res, const bf16* __restrict__ pf,
            const float* __restrict__ lns, const float* __restrict__ lnb,
            float* __restrict__ hout, bf16* __restrict__ hbout)
{
  const size_t MN = (size_t)2048*768;
  const int row = blockIdx.x;
  const int tid = threadIdx.x;           // 0..191
  const int wave = tid >> 6, lane = tid & 63;
  const int i0 = tid*4;
  const size_t base = (size_t)row*768 + i0;
  float4 x = *(const float4*)&res[base];
  #pragma unroll
  for (int p=0;p<NP;p++){
    ushort4 u = *(const ushort4*)&pf[p*MN + base];
    x.x += us2f(u.x); x.y += us2f(u.y); x.z += us2f(u.z); x.w += us2f(u.w);
  }
  float s1 = x.x+x.y+x.z+x.w;
  float s2 = x.x*x.x+x.y*x.y+x.z*x.z+x.w*x.w;
  #pragma unroll
  for (int m=32;m>=1;m>>=1){ s1 += __shfl_xor(s1,m); s2 += __shfl_xor(s2,m); }
  __shared__ float red[6];
  if (lane==0){ red[wave]=s1; red[3+wave]=s2; }
  __syncthreads();
  s1 = red[0]+red[1]+red[2];
  s2 = red[3]+red[4]+red[5];
  float mu = s1*(1.0f/768.0f);
  float var = s2*(1.0f/768.0f) - mu*mu;
  float rs = rsqrtf(var + 1e-5f);
  float4 sc = *(const float4*)&lns[i0];
  float4 bi = *(const float4*)&lnb[i0];
  float4 y = make_float4((x.x-mu)*rs*sc.x + bi.x, (x.y-mu)*rs*sc.y + bi.y,
                         (x.z-mu)*rs*sc.z + bi.z, (x.w-mu)*rs*sc.w + bi.w);
  *(float4*)&hout[base] = y;
  union { ushort4 u; bf16 h[4]; } pk;
  pk.h[0]=f2b(y.x); pk.h[1]=f2b(y.y); pk.h[2]=f2b(y.z); pk.h[3]=f2b(y.w);
  *(ushort4*)&hbout[base] = pk.u;
}

// ---------------- ALL-layer weight transpose -> swizzled BK-64 TILED layout ----------------
// grid (519, 12): single launch for all layers.
__global__ __launch_bounds__(256)
void prep_all(const float* __restrict__ Wq, const float* __restrict__ Wk,
              const float* __restrict__ Wv, const float* __restrict__ Wkg,
              const float* __restrict__ Wvg, const float* __restrict__ Wo,
              const float* __restrict__ Wf1, const float* __restrict__ Wf2,
              const float* __restrict__ bq, const float* __restrict__ bk,
              const float* __restrict__ bv, const float* __restrict__ bkg,
              const float* __restrict__ bvg,
              bf16* __restrict__ WcatT, bf16* __restrict__ WoT,
              bf16* __restrict__ Wf1T, bf16* __restrict__ Wf2T,
              float* __restrict__ bcat)
{
  const int b = blockIdx.x;
  const int l = blockIdx.y;
  const int tid = threadIdx.x;
  const size_t oHH = (size_t)l*768*768;
  const size_t oHF = (size_t)l*768*3072;
  const size_t oH  = (size_t)l*768;
  if (b >= 504) {
    int i = (b-504)*256 + tid;   // 0..3839
    int which = i / 768, j = i - which*768;
    float v;
    if      (which==0) v = bq[oH+j] * 0.125f;
    else if (which==1) v = bk[oH+j];
    else if (which==2) v = bv[oH+j];
    else if (which==3) v = bkg[oH+j];
    else               v = bvg[oH+j];
    bcat[(size_t)l*3840 + i] = v;
    return;
  }
  const float* src; bf16* dst; int N, KT64, p0, tk, k0, n0; float scale = 1.0f;
  if (b < 180) {
    int wsel = b/36, tile = b - wsel*36;
    int tkk = tile/3, tn = tile - tkk*3;
    if      (wsel==0){ src=Wq+oHH;  scale=0.125f; }
    else if (wsel==1){ src=Wk+oHH; }
    else if (wsel==2){ src=Wv+oHH; }
    else if (wsel==3){ src=Wkg+oHH; }
    else             { src=Wvg+oHH; }
    dst = WcatT + (size_t)l*5*768*768;
    N=768; KT64=12; k0=tkk*64; n0=tn*256; p0 = wsel*6 + tn*2; tk = tkk;
  } else if (b < 216) {
    int tile = b-180, tkk = tile/3, tn = tile - tkk*3;
    src = Wo+oHH; dst = WoT + (size_t)l*768*768;
    N=768; KT64=12; k0=tkk*64; n0=tn*256; p0 = tn*2; tk = tkk;
  } else if (b < 360) {
    int tile = b-216, tkk = tile/12, tn = tile - tkk*12;
    src = Wf1+oHF; dst = Wf1T + (size_t)l*768*3072;
    N=3072; KT64=12; k0=tkk*64; n0=tn*256; p0 = tn*2; tk = tkk;
  } else {
    int tile = b-360, tkk = tile/3, tn = tile - tkk*3;
    src = Wf2+oHF; dst = Wf2T + (size_t)l*768*3072;
    N=768; KT64=48; k0=tkk*64; n0=tn*256; p0 = tn*2; tk = tkk;
  }

  __shared__ bf16 t[64][264];
  const int wave = tid>>6, lane = tid&63;
  float4 v[16];
  #pragma unroll
  for (int i=0;i<16;i++){
    int r = i*4 + wave;
    v[i] = *(const float4*)&src[(size_t)(k0+r)*N + n0 + lane*4];
  }
  #pragma unroll
  for (int i=0;i<16;i++){
    int r = i*4 + wave;
    union { ushort4 u; bf16 h[4]; } pk;
    pk.h[0]=f2b(v[i].x*scale); pk.h[1]=f2b(v[i].y*scale);
    pk.h[2]=f2b(v[i].z*scale); pk.h[3]=f2b(v[i].w*scale);
    *(ushort4*)&t[r][lane*4] = pk.u;
  }
  __syncthreads();
  const int rr = tid>>1, half = tid&1;
  const int r7 = rr & 7;
  #pragma unroll
  for (int c=0;c<4;c++){
    const int pp = c>>1, tt = c&1;
    union { uint4 u[2]; bf16 h[16]; } pk;
    #pragma unroll
    for (int j=0;j<16;j++)
      pk.h[j] = t[tt*32 + half*16 + j][pp*128 + rr];
    bf16* base = dst + ((size_t)(p0+pp)*KT64 + tk)*8192 + rr*64;
    const int g0 = tt*4 + half*2;
    *(uint4*)(base + (((g0  ) ^ r7)<<3)) = pk.u[0];
    *(uint4*)(base + (((g0+1) ^ r7)<<3)) = pk.u[1];
  }
}

// ---------------- MFMA GEMM (BK=64, depth-2 counted-vmcnt, XOR-swizzled LDS) ----------------
template<int OUTF, int OUTB, int GELU, int KSPLIT, int VT>
__global__ __launch_bounds__(256)
void gemm_bt(const bf16* __restrict__ A, const bf16* __restrict__ Bt,
             const float* __restrict__ bias,
             bf16* __restrict__ pfb, bf16* __restrict__ outb,
             bf16* __restrict__ vt,
             int M, int N, int K)
{
  __shared__ bf16 As[2][128*64];
  __shared__ bf16 Bs[2][128*64];
  const int tid  = threadIdx.x;
  const int lane = tid & 63;
  const int wave = tid >> 6;
  const int wm = wave >> 1, wn = wave & 1;
  const int gx = gridDim.x, nwg = gx*gridDim.y;
  const int w  = blockIdx.y*gx + blockIdx.x;
  const int cpx = nwg >> 3;
  const int sw = (w & 7)*cpx + (w >> 3);
  const int bm = sw % gx, bn = sw / gx;
  const int bz = (KSPLIT>1) ? blockIdx.z : 0;
  const int fr = lane & 15;
  const int fk = lane >> 4;
  const int x7 = fr & 7;
  const int Ks = K / KSPLIT;
  const int nt = Ks >> 6;
  const int kbeg = bz * Ks;
  const int KT64 = K >> 6;

  const bf16* pa[4];
  int ldsA[4];
  #pragma unroll
  for (int i=0;i<4;i++){
    int s = i*256 + tid;
    int row = s >> 3, k8l = s & 7;
    pa[i] = A + (size_t)(bm*128 + row)*K + kbeg + ((k8l ^ (row&7))<<3);
    ldsA[i] = s*8;
  }
  const bf16* pB = Bt + ((size_t)bn*KT64 + (kbeg>>6))*8192;

  f32x4 acc[4][4];
  const f32x4 zero = {0.f,0.f,0.f,0.f};
  #pragma unroll
  for (int i=0;i<4;i++)
    #pragma unroll
    for (int j=0;j<4;j++) acc[i][j] = zero;

  #pragma unroll
  for (int i=0;i<4;i++) GLDS16(pa[i], &As[0][ldsA[i]]);
  #pragma unroll
  for (int i=0;i<4;i++){ int o=(i*256+tid)*8; GLDS16(pB+o, &Bs[0][o]); }
  if (nt > 1) {
    #pragma unroll
    for (int i=0;i<4;i++) GLDS16(pa[i]+64, &As[1][ldsA[i]]);
    #pragma unroll
    for (int i=0;i<4;i++){ int o=(i*256+tid)*8; GLDS16(pB+8192+o, &Bs[1][o]); }
  }

  for (int t = 0; t < nt; ++t) {
    const int cur = t & 1;
    if (t < nt-1) asm volatile("s_waitcnt vmcnt(8)" ::: "memory");
    else          asm volatile("s_waitcnt vmcnt(0)" ::: "memory");
    __builtin_amdgcn_s_barrier();
    __builtin_amdgcn_sched_barrier(0);

    bf16x8 af[2][4], bfr[2][4];
    #pragma unroll
    for (int kk=0;kk<2;kk++){
      #pragma unroll
      for (int m=0;m<4;m++)
        af[kk][m] = *reinterpret_cast<const bf16x8*>(
            &As[cur][(wm*64 + m*16 + fr)*64 + ((((kk<<2)+fk) ^ x7)<<3)]);
      #pragma unroll
      for (int n=0;n<4;n++)
        bfr[kk][n] = *reinterpret_cast<const bf16x8*>(
            &Bs[cur][(wn*64 + n*16 + fr)*64 + ((((kk<<2)+fk) ^ x7)<<3)]);
    }
    __builtin_amdgcn_s_setprio(1);
    #pragma unroll
    for (int kk=0;kk<2;kk++)
      #pragma unroll
      for (int m=0;m<4;m++)
        #pragma unroll
        for (int n=0;n<4;n++)
          acc[m][n] = __builtin_amdgcn_mfma_f32_16x16x32_bf16(af[kk][m], bfr[kk][n], acc[m][n], 0,0,0);
    __builtin_amdgcn_s_setprio(0);

    __builtin_amdgcn_s_barrier();
    __builtin_amdgcn_sched_barrier(0);
    if (t+2 < nt) {
      #pragma unroll
      for (int i=0;i<4;i++) GLDS16(pa[i] + (size_t)(t+2)*64, &As[cur][ldsA[i]]);
      #pragma unroll
      for (int i=0;i<4;i++){ int o=(i*256+tid)*8;
        GLDS16(pB + (size_t)(t+2)*8192 + o, &Bs[cur][o]); }
    }
  }

  const int row0 = bm*128 + wm*64 + (lane>>4)*4;
  const int col0 = bn*128 + wn*64 + fr;
  bf16* pfz = OUTF ? (pfb + (size_t)bz*M*N) : nullptr;
  #pragma unroll
  for (int n=0;n<4;n++){
    const int col = col0 + n*16;
    const float bv = (bz==0) ? bias[col] : 0.f;
    #pragma unroll
    for (int m=0;m<4;m++){
      const int r0 = row0 + m*16;
      union { ushort4 u; bf16 h[4]; } pk;
      #pragma unroll
      for (int r=0;r<4;r++){
        float x = acc[m][n][r] + bv;
        if (GELU) x = 0.5f*x*(1.0f + erff(x*0.70710678118f));
        size_t idx = (size_t)(r0+r)*N + col;
        pk.h[r] = f2b(x);
        if (OUTF) pfz[idx] = pk.h[r];
        if (OUTB) outb[idx] = pk.h[r];
      }
      if (VT) {
        if (col >= 1536 && col < 2304)
          *(ushort4*)&vt[(size_t)(col-1536)*2048 + r0] = pk.u;
      }
    }
  }
}

// ---------------- band + global attention (merged launch) ----------------
__global__ __launch_bounds__(256)
void band_attn(const bf16* __restrict__ qkv, const bf16* __restrict__ Vt,
               const float* __restrict__ h0, const float* __restrict__ Wqg,
               const float* __restrict__ bqg,
               const int* __restrict__ amask, const int* __restrict__ gmask,
               bf16* __restrict__ attn)
{
  const int c = blockIdx.x, n = blockIdx.y, rg = blockIdx.z;
  const int tid = threadIdx.x, wave = tid>>6, lane = tid&63;

  if (rg == 4) {
    if (c != 0) return;
    __shared__ float sg[2048];
    __shared__ float qh[64];
    __shared__ float redg[8];
    __shared__ float partg[4][64];
    {
      const int d = tid & 63;
      const int w = tid >> 6;
      const float* wp = Wqg + (size_t)(w*192)*768 + n*64 + d;
      float a = 0.f;
      #pragma unroll 8
      for (int k=0;k<192;k++) a += h0[w*192+k] * wp[(size_t)k*768];
      partg[w][d] = a;
    }
    __syncthreads();
    if (tid < 64)
      qh[tid] = (partg[0][tid]+partg[1][tid]+partg[2][tid]+partg[3][tid] + bqg[n*64+tid]) * 0.125f;
    __syncthreads();

    float smax = -3.0e38f;
    for (int p=0;p<8;p++){
      int s = p*256 + tid;
      const uint4* kr = (const uint4*)(qkv + (size_t)s*3840 + 2304 + n*64);
      float acc = 0.f;
      #pragma unroll
      for (int d8=0; d8<8; d8++){
        float f[8]; unpack8(kr[d8], f);
        #pragma unroll
        for (int e=0;e<8;e++) acc += f[e]*qh[d8*8+e];
      }
      if (amask[s] == 0) acc = -kNEG;
      sg[s] = acc;
      smax = fmaxf(smax, acc);
    }
    #pragma unroll
    for (int mk=32; mk>=1; mk>>=1) smax = fmaxf(smax, __shfl_xor(smax, mk));
    if (lane==0) redg[wave] = smax;
    __syncthreads();
    smax = fmaxf(fmaxf(redg[0],redg[1]),fmaxf(redg[2],redg[3]));
    float ssum = 0.f;
    for (int p=0;p<8;p++){
      int s = p*256 + tid;
      float e = __expf(sg[s]-smax);
      sg[s] = e;
      ssum += e;
    }
    #pragma unroll
    for (int mk=32; mk>=1; mk>>=1) ssum += __shfl_xor(ssum, mk);
    if (lane==0) redg[4+wave] = ssum;
    __syncthreads();
    float total = redg[4]+redg[5]+redg[6]+redg[7];
    __syncthreads();

    float o0=0.f,o1=0.f,o2=0.f,o3=0.f;
    const int base = wave*512;
    for (int s = base; s < base+512; s+=4){
      o0 += sg[s]   * b2f(qkv[(size_t)s*3840     + 3072 + n*64 + lane]);
      o1 += sg[s+1] * b2f(qkv[(size_t)(s+1)*3840 + 3072 + n*64 + lane]);
      o2 += sg[s+2] * b2f(qkv[(size_t)(s+2)*3840 + 3072 + n*64 + lane]);
      o3 += sg[s+3] * b2f(qkv[(size_t)(s+3)*3840 + 3072 + n*64 + lane]);
    }
    partg[wave][lane] = (o0+o1)+(o2+o3);
    __syncthreads();
    if (tid < 64) {
      float oo = (partg[0][tid]+partg[1][tid]+partg[2][tid]+partg[3][tid]) / total;
      attn[n*64+tid] = f2b(oo);
    }
    return;
  }

  // ---- band path ----
  const int fr = lane & 15, fk = lane >> 4;
  const int jj = tid >> 2, seg = tid & 3;

  __shared__ __attribute__((aligned(16))) bf16 q_s[64][72];
  __shared__ __attribute__((aligned(16))) bf16 k_s[2][64][72];
  __shared__ __attribute__((aligned(16))) bf16 vt_s[2][64][72];
  __shared__ __attribute__((aligned(16))) bf16 p_s[4][16][72];
  __shared__ int  okk_s[768];
  __shared__ float kv0[2][64];

  {
    const uint4* src = (const uint4*)(qkv + (size_t)(c*256 + rg*64 + jj)*3840 + n*64 + seg*16);
    *(uint4*)&q_s[jj][seg*16]   = src[0];
    *(uint4*)&q_s[jj][seg*16+8] = src[1];
  }
  #pragma unroll
  for (int p=0;p<3;p++){
    int j = tid + p*256;
    int kpos = c*256 + j - 256;
    int ok = 0;
    if (kpos >= 0 && kpos < 2048) ok = (amask[kpos] != 0) && (gmask[kpos] == 0);
    okk_s[j] = ok;
  }
  if (tid < 64)       kv0[0][tid]    = b2f(qkv[768  + n*64 + tid]);
  else if (tid < 128) kv0[1][tid-64] = b2f(qkv[1536 + n*64 + (tid-64)]);

  auto loadK = [&](int kt, uint4& a, uint4& b){
    int kpos = c*256 + kt*64 + jj - 256;
    int kq = kpos < 0 ? 0 : (kpos > 2047 ? 2047 : kpos);
    const uint4* ks = (const uint4*)(qkv + (size_t)kq*3840 + 768 + n*64 + seg*16);
    a = ks[0]; b = ks[1];
  };
  auto loadV = [&](int kt, uint4& a, uint4& b){
    int base = c*256 + kt*64 - 256;
    int sb = (base < 0 || base > 2048-64) ? 0 : base;
    const uint4* vs = (const uint4*)(Vt + (size_t)(n*64 + jj)*2048 + sb + seg*8);
    a = vs[0]; b = vs[4];
  };

  // clip to tiles with at least one in-range key
  const int kt_lo = (c==0) ? ((rg > 4) ? rg : 4) : rg;
  int kt_hi = rg+8 < 11 ? rg+8 : 11;
  const int clip = (2303 - c*256) >> 6;
  if (kt_hi > clip) kt_hi = clip;

  uint4 ka,kb,va,vb;
  loadK(kt_lo,ka,kb); loadV(kt_lo,va,vb);
  *(uint4*)&k_s[0][jj][seg*16]    = ka;
  *(uint4*)&k_s[0][jj][seg*16+8]  = kb;
  *(uint4*)&vt_s[0][jj][seg*8]    = va;
  *(uint4*)&vt_s[0][jj][seg*8+32] = vb;

  float lsum[4];
  f32x4 out[4];
  const f32x4 zero = {0.f,0.f,0.f,0.f};
  #pragma unroll
  for (int r=0;r<4;r++) lsum[r] = 0.f;
  #pragma unroll
  for (int dt=0;dt<4;dt++) out[dt] = zero;

  int cur = 0;
  for (int kt = kt_lo; kt <= kt_hi; kt++) {
    const bool pf = (kt < kt_hi);
    if (pf){ loadK(kt+1,ka,kb); loadV(kt+1,va,vb); }
    __syncthreads();

    f32x4 s[4];
    #pragma unroll
    for (int ct=0;ct<4;ct++) s[ct] = zero;
    __builtin_amdgcn_s_setprio(1);
    #pragma unroll
    for (int ks=0;ks<2;ks++){
      bf16x8 aq = *reinterpret_cast<const bf16x8*>(&q_s[wave*16 + fr][ks*32 + fk*8]);
      #pragma unroll
      for (int ct=0;ct<4;ct++){
        bf16x8 bk = *reinterpret_cast<const bf16x8*>(&k_s[cur][ct*16 + fr][ks*32 + fk*8]);
        s[ct] = __builtin_amdgcn_mfma_f32_16x16x32_bf16(aq, bk, s[ct], 0,0,0);
      }
    }
    __builtin_amdgcn_s_setprio(0);
    const int qbase = rg*64 + wave*16 + fk*4;
    // max-free softmax: P = exp(S) directly; masked -> exp(-1e9) = 0
    #pragma unroll
    for (int ct=0;ct<4;ct++){
      int j = kt*64 + ct*16 + fr;
      int okj = okk_s[j];
      #pragma unroll
      for (int r=0;r<4;r++){
        unsigned rel = (unsigned)(j - (qbase + r));
        float sv = (okj && rel <= 512u) ? s[ct][r] : -kNEG;
        float p = __expf(sv);
        lsum[r] += p;
        p_s[wave][fk*4 + r][ct*16 + fr] = f2b(p);
      }
    }
    __builtin_amdgcn_s_setprio(1);
    #pragma unroll
    for (int ks=0;ks<2;ks++){
      bf16x8 ap = *reinterpret_cast<const bf16x8*>(&p_s[wave][fr][ks*32 + fk*8]);
      #pragma unroll
      for (int dt=0;dt<4;dt++){
        bf16x8 bv = *reinterpret_cast<const bf16x8*>(&vt_s[cur][dt*16 + fr][ks*32 + fk*8]);
        out[dt] = __builtin_amdgcn_mfma_f32_16x16x32_bf16(ap, bv, out[dt], 0,0,0);
      }
    }
    __builtin_amdgcn_s_setprio(0);

    if (pf){
      *(uint4*)&k_s[cur^1][jj][seg*16]    = ka;
      *(uint4*)&k_s[cur^1][jj][seg*16+8]  = kb;
      *(uint4*)&vt_s[cur^1][jj][seg*8]    = va;
      *(uint4*)&vt_s[cur^1][jj][seg*8+32] = vb;
      cur ^= 1;
    }
  }

  // single end-of-loop row-sum reduce + global column + finalize
  const bool okg = (amask[0] != 0);
  #pragma unroll
  for (int r=0;r<4;r++){
    const int row16 = fk*4 + r;
    float ts = lsum[r];
    #pragma unroll
    for (int mk=8; mk>=1; mk>>=1) ts += __shfl_xor(ts, mk);
    float sp = 0.f;
    #pragma unroll
    for (int e=0;e<4;e++){
      int d = fr*4 + e;
      sp += b2f(q_s[wave*16 + row16][d]) * kv0[0][d];
    }
    #pragma unroll
    for (int mk=8; mk>=1; mk>>=1) sp += __shfl_xor(sp, mk);
    float pg = okg ? __expf(sp) : 0.f;
    float lf = ts + pg;
    const int srow = c*256 + rg*64 + wave*16 + row16;
    if (srow != 0) {
      #pragma unroll
      for (int dt=0;dt<4;dt++){
        int d = dt*16 + fr;
        float o = (out[dt][r] + pg*kv0[1][d]) / lf;
        attn[(size_t)srow*768 + n*64 + d] = f2b(o);
      }
    }
  }
}

// ---------------- head, parallelized: 4 small kernels ----------------
__global__ __launch_bounds__(256)
void head_p1(const float* __restrict__ h0, const float* __restrict__ dw,
             float* __restrict__ pd)
{
  const int col = blockIdx.x*256 + threadIdx.x;
  const int z = blockIdx.y;
  const int k0 = z*96;
  float acc = 0.f;
  #pragma unroll 8
  for (int k=0;k<96;k++) acc += h0[k0+k]*dw[(size_t)(k0+k)*768 + col];
  pd[z*768 + col] = acc;
}

__global__ __launch_bounds__(256)
void head_y(const float* __restrict__ pd, const float* __restrict__ db,
            float* __restrict__ yv)
{
  const int col = blockIdx.x*256 + threadIdx.x;
  float a = 0.f;
  #pragma unroll
  for (int z=0;z<8;z++) a += pd[z*768 + col];
  yv[col] = tanhf(a + db[col]);
}

__global__ __launch_bounds__(256)
void head_p2(const float* __restrict__ yv, const float* __restrict__ ow,
             float* __restrict__ po)
{
  const int col = threadIdx.x;
  const int z = blockIdx.x;
  const int k0 = z*96;
  float acc = 0.f;
  #pragma unroll 8
  for (int k=0;k<96;k++) acc += yv[k0+k]*ow[(size_t)(k0+k)*256 + col];
  po[z*256 + col] = acc;
}

__global__ __launch_bounds__(256)
void head_fin(const float* __restrict__ po, const float* __restrict__ ob,
              float* __restrict__ out)
{
  const int col = threadIdx.x;
  float a = 0.f;
  #pragma unroll
  for (int z=0;z<8;z++) a += po[z*256 + col];
  out[col] = a + ob[col];
}

// ---------------- host ----------------
extern "C" void kernel_launch(void* const* d_in, const int* in_sizes, int n_in,
                              void* d_out, int out_size, void* d_ws, size_t ws_size,
                              hipStream_t stream)
{
  const int*   ids   = (const int*)d_in[0];
  const int*   amask = (const int*)d_in[1];
  const int*   gmask = (const int*)d_in[2];
  const float* wemb  = (const float*)d_in[3];
  const float* pemb  = (const float*)d_in[4];
  const float* elns  = (const float*)d_in[5];
  const float* elnb  = (const float*)d_in[6];
  const float* Wq    = (const float*)d_in[7];
  const float* bq    = (const float*)d_in[8];
  const float* Wk    = (const float*)d_in[9];
  const float* bk    = (const float*)d_in[10];
  const float* Wv    = (const float*)d_in[11];
  const float* bv    = (const float*)d_in[12];
  const float* Wqg   = (const float*)d_in[13];
  const float* bqg   = (const float*)d_in[14];
  const float* Wkg   = (const float*)d_in[15];
  const float* bkg   = (const float*)d_in[16];
  const float* Wvg   = (const float*)d_in[17];
  const float* bvg   = (const float*)d_in[18];
  const float* Wo    = (const float*)d_in[19];
  const float* bo    = (const float*)d_in[20];
  const float* ln1s  = (const float*)d_in[21];
  const float* ln1b  = (const float*)d_in[22];
  const float* Wf1   = (const float*)d_in[23];
  const float* bf1   = (const float*)d_in[24];
  const float* Wf2   = (const float*)d_in[25];
  const float* bf2   = (const float*)d_in[26];
  const float* ln2s  = (const float*)d_in[27];
  const float* ln2b  = (const float*)d_in[28];
  const float* dw    = (const float*)d_in[29];
  const float* db    = (const float*)d_in[30];
  const float* ow    = (const float*)d_in[31];
  const float* ob    = (const float*)d_in[32];

  char* ws = (char*)d_ws;
  size_t off = 0;
  auto alloc = [&](size_t bytes)->char*{
    char* p = ws + off; off += (bytes + 255) & ~(size_t)255; return p;
  };
  float* h     = (float*)alloc((size_t)2048*768*4);
  bf16*  hb    = (bf16*) alloc((size_t)2048*768*2);
  float* h2    = (float*)alloc((size_t)2048*768*4);
  bf16*  h2b   = (bf16*) alloc((size_t)2048*768*2);
  bf16*  qkv   = (bf16*) alloc((size_t)2048*3840*2);
  bf16*  att   = (bf16*) alloc((size_t)2048*768*2);
  bf16*  f1    = (bf16*) alloc((size_t)2048*3072*2);
  bf16*  Vtb   = (bf16*) alloc((size_t)768*2048*2);    // V^T per layer [head*64+d][s]
  bf16*  pfb   = (bf16*) alloc((size_t)4*2048*768*2);  // split-K partials (bf16)
  bf16*  WcatT = (bf16*) alloc((size_t)12*5*768*768*2);
  bf16*  WoT   = (bf16*) alloc((size_t)12*768*768*2);
  bf16*  Wf1T  = (bf16*) alloc((size_t)12*768*3072*2);
  bf16*  Wf2T  = (bf16*) alloc((size_t)12*768*3072*2);
  float* bcat  = (float*)alloc((size_t)12*3840*4);
  float* pd    = (float*)alloc((size_t)8*768*4);
  float* yv    = (float*)alloc((size_t)768*4);
  float* po    = (float*)alloc((size_t)8*256*4);

  prep_all<<<dim3(519,12),256,0,stream>>>(Wq, Wk, Wv, Wkg, Wvg, Wo, Wf1, Wf2,
                                          bq, bk, bv, bkg, bvg,
                                          WcatT, WoT, Wf1T, Wf2T, bcat);
  embed_ln<<<2048,192,0,stream>>>(ids, wemb, pemb, elns, elnb, h, hb);

  for (int l=0; l<12; l++) {
    const size_t oHH = (size_t)l*768*768;
    const size_t oH  = (size_t)l*768;
    const size_t oF  = (size_t)l*3072;
    const bf16* WcatT_l = WcatT + (size_t)l*5*768*768;
    const bf16* WoT_l   = WoT   + (size_t)l*768*768;
    const bf16* Wf1T_l  = Wf1T  + (size_t)l*768*3072;
    const bf16* Wf2T_l  = Wf2T  + (size_t)l*768*3072;
    const float* bcat_l = bcat  + (size_t)l*3840;

    gemm_bt<0,1,0,1,1><<<dim3(16,30),256,0,stream>>>(hb, WcatT_l, bcat_l, nullptr, qkv,
                                                     Vtb, 2048, 3840, 768);
    band_attn<<<dim3(8,12,5),256,0,stream>>>(qkv, Vtb, h, Wqg+oHH, bqg+oH,
                                             amask, gmask, att);
    gemm_bt<1,0,0,3,0><<<dim3(16,6,3),256,0,stream>>>(att, WoT_l, bo+oH, pfb, nullptr,
                                                      nullptr, 2048, 768, 768);
    add_ln<3><<<2048,192,0,stream>>>(h, pfb, ln1s+oH, ln1b+oH, h2, h2b);
    gemm_bt<0,1,1,1,0><<<dim3(16,24),256,0,stream>>>(h2b, Wf1T_l, bf1+oF, nullptr, f1,
                                                     nullptr, 2048, 3072, 768);
    gemm_bt<1,0,0,3,0><<<dim3(16,6,3),256,0,stream>>>(f1, Wf2T_l, bf2+oH, pfb, nullptr,
                                                      nullptr, 2048, 768, 3072);
    add_ln<3><<<2048,192,0,stream>>>(h2, pfb, ln2s+oH, ln2b+oH, h, hb);
  }

  head_p1<<<dim3(3,8),256,0,stream>>>(h, dw, pd);
  head_y<<<3,256,0,stream>>>(pd, db, yv);
  head_p2<<<8,256,0,stream>>>(yv, ow, po);
  head_fin<<<1,256,0,stream>>>(po, ob, (float*)d_out);
}

// Round 15
// 2111.443 us; speedup vs baseline: 1.0628x; 1.0120x over previous
//
#include <hip/hip_runtime.h>
#include <hip/hip_bf16.h>

typedef __hip_bfloat16 bf16;
using bf16x8 = __attribute__((ext_vector_type(8))) short;
using f32x4  = __attribute__((ext_vector_type(4))) float;

#define kNEG 1.0e9f

__device__ __forceinline__ float b2f(bf16 x){ return __bfloat162float(x); }
__device__ __forceinline__ bf16  f2b(float x){ return __float2bfloat16(x); }
__device__ __forceinline__ float us2f(unsigned short u){ return __uint_as_float(((unsigned)u)<<16); }

// fast erf (Abramowitz-Stegun 7.1.26, max abs err 1.5e-7)
__device__ __forceinline__ float erf_fast(float z){
  float az = fabsf(z);
  float t = __frcp_rn(fmaf(0.3275911f, az, 1.0f));
  float p = t*fmaf(t, fmaf(t, fmaf(t, fmaf(t, 1.061405429f, -1.453152027f),
                                    1.421413741f), -0.284496736f), 0.254829592f);
  float e = 1.0f - p*__expf(-az*az);
  return copysignf(e, z);
}

#define GLDS16(gp, lp) __builtin_amdgcn_global_load_lds( \
    (const __attribute__((address_space(1))) void*)(gp), \
    (__attribute__((address_space(3))) void*)(lp), 16, 0, 0)

__device__ __forceinline__ void unpack8(uint4 u, float* f){
  f[0]=__uint_as_float(u.x<<16); f[1]=__uint_as_float(u.x&0xffff0000u);
  f[2]=__uint_as_float(u.y<<16); f[3]=__uint_as_float(u.y&0xffff0000u);
  f[4]=__uint_as_float(u.z<<16); f[5]=__uint_as_float(u.z&0xffff0000u);
  f[6]=__uint_as_float(u.w<<16); f[7]=__uint_as_float(u.w&0xffff0000u);
}

// ---------------- embedding + LN (vectorized, 192 threads/row) ----------------
__global__ __launch_bounds__(192)
void embed_ln(const int* __restrict__ ids, const float* __restrict__ wemb,
              const float* __restrict__ pemb, const float* __restrict__ lns,
              const float* __restrict__ lnb, float* __restrict__ hout,
              bf16* __restrict__ hbout)
{
  const int row = blockIdx.x;
  const int tid = threadIdx.x;           // 0..191
  const int wave = tid >> 6, lane = tid & 63;
  const int id = ids[row];
  const int i0 = tid*4;
  float4 a = *(const float4*)&wemb[(size_t)id*768 + i0];
  float4 b = *(const float4*)&pemb[(size_t)row*768 + i0];
  float4 x = make_float4(a.x+b.x, a.y+b.y, a.z+b.z, a.w+b.w);
  float s1 = x.x+x.y+x.z+x.w;
  float s2 = x.x*x.x+x.y*x.y+x.z*x.z+x.w*x.w;
  #pragma unroll
  for (int m=32;m>=1;m>>=1){ s1 += __shfl_xor(s1,m); s2 += __shfl_xor(s2,m); }
  __shared__ float red[6];
  if (lane==0){ red[wave]=s1; red[3+wave]=s2; }
  __syncthreads();
  s1 = red[0]+red[1]+red[2];
  s2 = red[3]+red[4]+red[5];
  float mu = s1*(1.0f/768.0f);
  float var = s2*(1.0f/768.0f) - mu*mu;
  float rs = rsqrtf(var + 1e-5f);
  float4 sc = *(const float4*)&lns[i0];
  float4 bi = *(const float4*)&lnb[i0];
  float4 y = make_float4((x.x-mu)*rs*sc.x + bi.x, (x.y-mu)*rs*sc.y + bi.y,
                         (x.z-mu)*rs*sc.z + bi.z, (x.w-mu)*rs*sc.w + bi.w);
  *(float4*)&hout[(size_t)row*768 + i0] = y;
  union { ushort4 u; bf16 h[4]; } pk;
  pk.h[0]=f2b(y.x); pk.h[1]=f2b(y.y); pk.h[2]=f2b(y.z); pk.h[3]=f2b(y.w);
  *(ushort4*)&hbout[(size_t)row*768 + i0] = pk.u;
}

// ---------------- residual add (NP bf16 partials) + LN (vectorized) ----------------
template<int NP>
__global__ __launch_bounds__(192)
void add_ln(const float* __restrict__ res, const bf16* __restrict__ pf,
            const float* __restrict__ lns, const float* __restrict__ lnb,
            float* __restrict__ hout, bf16* __restrict__ hbout)
{
  const size_t MN = (size_t)2048*768;
  const int row = blockIdx.x;
  const int tid = threadIdx.x;           // 0..191
  const int wave = tid >> 6, lane = tid & 63;
  const int i0 = tid*4;
  const size_t base = (size_t)row*768 + i0;
  float4 x = *(const float4*)&res[base];
  #pragma unroll
  for (int p=0;p<NP;p++){
    ushort4 u = *(const ushort4*)&pf[p*MN + base];
    x.x += us2f(u.x); x.y += us2f(u.y); x.z += us2f(u.z); x.w += us2f(u.w);
  }
  float s1 = x.x+x.y+x.z+x.w;
  float s2 = x.x*x.x+x.y*x.y+x.z*x.z+x.w*x.w;
  #pragma unroll
  for (int m=32;m>=1;m>>=1){ s1 += __shfl_xor(s1,m); s2 += __shfl_xor(s2,m); }
  __shared__ float red[6];
  if (lane==0){ red[wave]=s1; red[3+wave]=s2; }
  __syncthreads();
  s1 = red[0]+red[1]+red[2];
  s2 = red[3]+red[4]+red[5];
  float mu = s1*(1.0f/768.0f);
  float var = s2*(1.0f/768.0f) - mu*mu;
  float rs = rsqrtf(var + 1e-5f);
  float4 sc = *(const float4*)&lns[i0];
  float4 bi = *(const float4*)&lnb[i0];
  float4 y = make_float4((x.x-mu)*rs*sc.x + bi.x, (x.y-mu)*rs*sc.y + bi.y,
                         (x.z-mu)*rs*sc.z + bi.z, (x.w-mu)*rs*sc.w + bi.w);
  *(float4*)&hout[base] = y;
  union { ushort4 u; bf16 h[4]; } pk;
  pk.h[0]=f2b(y.x); pk.h[1]=f2b(y.y); pk.h[2]=f2b(y.z); pk.h[3]=f2b(y.w);
  *(ushort4*)&hbout[base] = pk.u;
}

// ---------------- ALL-layer weight transpose -> swizzled BK-64 TILED layout ----------------
__global__ __launch_bounds__(256)
void prep_all(const float* __restrict__ Wq, const float* __restrict__ Wk,
              const float* __restrict__ Wv, const float* __restrict__ Wkg,
              const float* __restrict__ Wvg, const float* __restrict__ Wo,
              const float* __restrict__ Wf1, const float* __restrict__ Wf2,
              const float* __restrict__ bq, const float* __restrict__ bk,
              const float* __restrict__ bv, const float* __restrict__ bkg,
              const float* __restrict__ bvg,
              bf16* __restrict__ WcatT, bf16* __restrict__ WoT,
              bf16* __restrict__ Wf1T, bf16* __restrict__ Wf2T,
              float* __restrict__ bcat)
{
  const int b = blockIdx.x;
  const int l = blockIdx.y;
  const int tid = threadIdx.x;
  const size_t oHH = (size_t)l*768*768;
  const size_t oHF = (size_t)l*768*3072;
  const size_t oH  = (size_t)l*768;
  if (b >= 504) {
    int i = (b-504)*256 + tid;   // 0..3839
    int which = i / 768, j = i - which*768;
    float v;
    if      (which==0) v = bq[oH+j] * 0.125f;
    else if (which==1) v = bk[oH+j];
    else if (which==2) v = bv[oH+j];
    else if (which==3) v = bkg[oH+j];
    else               v = bvg[oH+j];
    bcat[(size_t)l*3840 + i] = v;
    return;
  }
  const float* src; bf16* dst; int N, KT64, p0, tk, k0, n0; float scale = 1.0f;
  if (b < 180) {
    int wsel = b/36, tile = b - wsel*36;
    int tkk = tile/3, tn = tile - tkk*3;
    if      (wsel==0){ src=Wq+oHH;  scale=0.125f; }
    else if (wsel==1){ src=Wk+oHH; }
    else if (wsel==2){ src=Wv+oHH; }
    else if (wsel==3){ src=Wkg+oHH; }
    else             { src=Wvg+oHH; }
    dst = WcatT + (size_t)l*5*768*768;
    N=768; KT64=12; k0=tkk*64; n0=tn*256; p0 = wsel*6 + tn*2; tk = tkk;
  } else if (b < 216) {
    int tile = b-180, tkk = tile/3, tn = tile - tkk*3;
    src = Wo+oHH; dst = WoT + (size_t)l*768*768;
    N=768; KT64=12; k0=tkk*64; n0=tn*256; p0 = tn*2; tk = tkk;
  } else if (b < 360) {
    int tile = b-216, tkk = tile/12, tn = tile - tkk*12;
    src = Wf1+oHF; dst = Wf1T + (size_t)l*768*3072;
    N=3072; KT64=12; k0=tkk*64; n0=tn*256; p0 = tn*2; tk = tkk;
  } else {
    int tile = b-360, tkk = tile/3, tn = tile - tkk*3;
    src = Wf2+oHF; dst = Wf2T + (size_t)l*768*3072;
    N=768; KT64=48; k0=tkk*64; n0=tn*256; p0 = tn*2; tk = tkk;
  }

  __shared__ bf16 t[64][264];
  const int wave = tid>>6, lane = tid&63;
  float4 v[16];
  #pragma unroll
  for (int i=0;i<16;i++){
    int r = i*4 + wave;
    v[i] = *(const float4*)&src[(size_t)(k0+r)*N + n0 + lane*4];
  }
  #pragma unroll
  for (int i=0;i<16;i++){
    int r = i*4 + wave;
    union { ushort4 u; bf16 h[4]; } pk;
    pk.h[0]=f2b(v[i].x*scale); pk.h[1]=f2b(v[i].y*scale);
    pk.h[2]=f2b(v[i].z*scale); pk.h[3]=f2b(v[i].w*scale);
    *(ushort4*)&t[r][lane*4] = pk.u;
  }
  __syncthreads();
  const int rr = tid>>1, half = tid&1;
  const int r7 = rr & 7;
  #pragma unroll
  for (int c=0;c<4;c++){
    const int pp = c>>1, tt = c&1;
    union { uint4 u[2]; bf16 h[16]; } pk;
    #pragma unroll
    for (int j=0;j<16;j++)
      pk.h[j] = t[tt*32 + half*16 + j][pp*128 + rr];
    bf16* base = dst + ((size_t)(p0+pp)*KT64 + tk)*8192 + rr*64;
    const int g0 = tt*4 + half*2;
    *(uint4*)(base + (((g0  ) ^ r7)<<3)) = pk.u[0];
    *(uint4*)(base + (((g0+1) ^ r7)<<3)) = pk.u[1];
  }
}

// ---------------- MFMA GEMM (BK=64, depth-2 counted-vmcnt, XOR-swizzled LDS) ----------------
template<int OUTF, int OUTB, int GELU, int KSPLIT, int VT>
__global__ __launch_bounds__(256)
void gemm_bt(const bf16* __restrict__ A, const bf16* __restrict__ Bt,
             const float* __restrict__ bias,
             bf16* __restrict__ pfb, bf16* __restrict__ outb,
             bf16* __restrict__ vt,
             int M, int N, int K)
{
  __shared__ bf16 As[2][128*64];
  __shared__ bf16 Bs[2][128*64];
  const int tid  = threadIdx.x;
  const int lane = tid & 63;
  const int wave = tid >> 6;
  const int wm = wave >> 1, wn = wave & 1;
  const int gx = gridDim.x, nwg = gx*gridDim.y;
  const int w  = blockIdx.y*gx + blockIdx.x;
  const int cpx = nwg >> 3;
  const int sw = (w & 7)*cpx + (w >> 3);
  const int bm = sw % gx, bn = sw / gx;
  const int bz = (KSPLIT>1) ? blockIdx.z : 0;
  const int fr = lane & 15;
  const int fk = lane >> 4;
  const int x7 = fr & 7;
  const int Ks = K / KSPLIT;
  const int nt = Ks >> 6;
  const int kbeg = bz * Ks;
  const int KT64 = K >> 6;

  const bf16* pa[4];
  int ldsA[4];
  #pragma unroll
  for (int i=0;i<4;i++){
    int s = i*256 + tid;
    int row = s >> 3, k8l = s & 7;
    pa[i] = A + (size_t)(bm*128 + row)*K + kbeg + ((k8l ^ (row&7))<<3);
    ldsA[i] = s*8;
  }
  const bf16* pB = Bt + ((size_t)bn*KT64 + (kbeg>>6))*8192;

  f32x4 acc[4][4];
  const f32x4 zero = {0.f,0.f,0.f,0.f};
  #pragma unroll
  for (int i=0;i<4;i++)
    #pragma unroll
    for (int j=0;j<4;j++) acc[i][j] = zero;

  #pragma unroll
  for (int i=0;i<4;i++) GLDS16(pa[i], &As[0][ldsA[i]]);
  #pragma unroll
  for (int i=0;i<4;i++){ int o=(i*256+tid)*8; GLDS16(pB+o, &Bs[0][o]); }
  if (nt > 1) {
    #pragma unroll
    for (int i=0;i<4;i++) GLDS16(pa[i]+64, &As[1][ldsA[i]]);
    #pragma unroll
    for (int i=0;i<4;i++){ int o=(i*256+tid)*8; GLDS16(pB+8192+o, &Bs[1][o]); }
  }

  for (int t = 0; t < nt; ++t) {
    const int cur = t & 1;
    if (t < nt-1) asm volatile("s_waitcnt vmcnt(8)" ::: "memory");
    else          asm volatile("s_waitcnt vmcnt(0)" ::: "memory");
    __builtin_amdgcn_s_barrier();
    __builtin_amdgcn_sched_barrier(0);

    bf16x8 af[2][4], bfr[2][4];
    #pragma unroll
    for (int kk=0;kk<2;kk++){
      #pragma unroll
      for (int m=0;m<4;m++)
        af[kk][m] = *reinterpret_cast<const bf16x8*>(
            &As[cur][(wm*64 + m*16 + fr)*64 + ((((kk<<2)+fk) ^ x7)<<3)]);
      #pragma unroll
      for (int n=0;n<4;n++)
        bfr[kk][n] = *reinterpret_cast<const bf16x8*>(
            &Bs[cur][(wn*64 + n*16 + fr)*64 + ((((kk<<2)+fk) ^ x7)<<3)]);
    }
    __builtin_amdgcn_s_setprio(1);
    #pragma unroll
    for (int kk=0;kk<2;kk++)
      #pragma unroll
      for (int m=0;m<4;m++)
        #pragma unroll
        for (int n=0;n<4;n++)
          acc[m][n] = __builtin_amdgcn_mfma_f32_16x16x32_bf16(af[kk][m], bfr[kk][n], acc[m][n], 0,0,0);
    __builtin_amdgcn_s_setprio(0);

    __builtin_amdgcn_s_barrier();
    __builtin_amdgcn_sched_barrier(0);
    if (t+2 < nt) {
      #pragma unroll
      for (int i=0;i<4;i++) GLDS16(pa[i] + (size_t)(t+2)*64, &As[cur][ldsA[i]]);
      #pragma unroll
      for (int i=0;i<4;i++){ int o=(i*256+tid)*8;
        GLDS16(pB + (size_t)(t+2)*8192 + o, &Bs[cur][o]); }
    }
  }

  const int row0 = bm*128 + wm*64 + (lane>>4)*4;
  const int col0 = bn*128 + wn*64 + fr;
  bf16* pfz = OUTF ? (pfb + (size_t)bz*M*N) : nullptr;
  #pragma unroll
  for (int n=0;n<4;n++){
    const int col = col0 + n*16;
    const float bv = (bz==0) ? bias[col] : 0.f;
    #pragma unroll
    for (int m=0;m<4;m++){
      const int r0 = row0 + m*16;
      union { ushort4 u; bf16 h[4]; } pk;
      #pragma unroll
      for (int r=0;r<4;r++){
        float x = acc[m][n][r] + bv;
        if (GELU) x = 0.5f*x*(1.0f + erf_fast(x*0.70710678118f));
        size_t idx = (size_t)(r0+r)*N + col;
        pk.h[r] = f2b(x);
        if (OUTF) pfz[idx] = pk.h[r];
        if (OUTB) outb[idx] = pk.h[r];
      }
      if (VT) {
        if (col >= 1536 && col < 2304)
          *(ushort4*)&vt[(size_t)(col-1536)*2048 + r0] = pk.u;
      }
    }
  }
}

// ---------------- band + global attention (merged launch) ----------------
__global__ __launch_bounds__(256)
void band_attn(const bf16* __restrict__ qkv, const bf16* __restrict__ Vt,
               const float* __restrict__ h0, const float* __restrict__ Wqg,
               const float* __restrict__ bqg,
               const int* __restrict__ amask, const int* __restrict__ gmask,
               bf16* __restrict__ attn)
{
  const int c = blockIdx.x, n = blockIdx.y, rg = blockIdx.z;
  const int tid = threadIdx.x, wave = tid>>6, lane = tid&63;

  if (rg == 4) {
    if (c != 0) return;
    __shared__ float sg[2048];
    __shared__ float qh[64];
    __shared__ float redg[8];
    __shared__ float partg[4][64];
    {
      const int d = tid & 63;
      const int w = tid >> 6;
      const float* wp = Wqg + (size_t)(w*192)*768 + n*64 + d;
      float a = 0.f;
      #pragma unroll 8
      for (int k=0;k<192;k++) a += h0[w*192+k] * wp[(size_t)k*768];
      partg[w][d] = a;
    }
    __syncthreads();
    if (tid < 64)
      qh[tid] = (partg[0][tid]+partg[1][tid]+partg[2][tid]+partg[3][tid] + bqg[n*64+tid]) * 0.125f;
    __syncthreads();

    float smax = -3.0e38f;
    for (int p=0;p<8;p++){
      int s = p*256 + tid;
      const uint4* kr = (const uint4*)(qkv + (size_t)s*3840 + 2304 + n*64);
      float acc = 0.f;
      #pragma unroll
      for (int d8=0; d8<8; d8++){
        float f[8]; unpack8(kr[d8], f);
        #pragma unroll
        for (int e=0;e<8;e++) acc += f[e]*qh[d8*8+e];
      }
      if (amask[s] == 0) acc = -kNEG;
      sg[s] = acc;
      smax = fmaxf(smax, acc);
    }
    #pragma unroll
    for (int mk=32; mk>=1; mk>>=1) smax = fmaxf(smax, __shfl_xor(smax, mk));
    if (lane==0) redg[wave] = smax;
    __syncthreads();
    smax = fmaxf(fmaxf(redg[0],redg[1]),fmaxf(redg[2],redg[3]));
    float ssum = 0.f;
    for (int p=0;p<8;p++){
      int s = p*256 + tid;
      float e = __expf(sg[s]-smax);
      sg[s] = e;
      ssum += e;
    }
    #pragma unroll
    for (int mk=32; mk>=1; mk>>=1) ssum += __shfl_xor(ssum, mk);
    if (lane==0) redg[4+wave] = ssum;
    __syncthreads();
    float total = redg[4]+redg[5]+redg[6]+redg[7];
    __syncthreads();

    float o0=0.f,o1=0.f,o2=0.f,o3=0.f;
    const int base = wave*512;
    for (int s = base; s < base+512; s+=4){
      o0 += sg[s]   * b2f(qkv[(size_t)s*3840     + 3072 + n*64 + lane]);
      o1 += sg[s+1] * b2f(qkv[(size_t)(s+1)*3840 + 3072 + n*64 + lane]);
      o2 += sg[s+2] * b2f(qkv[(size_t)(s+2)*3840 + 3072 + n*64 + lane]);
      o3 += sg[s+3] * b2f(qkv[(size_t)(s+3)*3840 + 3072 + n*64 + lane]);
    }
    partg[wave][lane] = (o0+o1)+(o2+o3);
    __syncthreads();
    if (tid < 64) {
      float oo = (partg[0][tid]+partg[1][tid]+partg[2][tid]+partg[3][tid]) / total;
      attn[n*64+tid] = f2b(oo);
    }
    return;
  }

  // ---- band path ----
  const int fr = lane & 15, fk = lane >> 4;
  const int jj = tid >> 2, seg = tid & 3;

  __shared__ __attribute__((aligned(16))) bf16 q_s[64][72];
  __shared__ __attribute__((aligned(16))) bf16 k_s[2][64][72];
  __shared__ __attribute__((aligned(16))) bf16 vt_s[2][64][72];
  __shared__ __attribute__((aligned(16))) bf16 p_s[4][16][72];
  __shared__ int  okk_s[768];
  __shared__ float kv0[2][64];

  {
    const uint4* src = (const uint4*)(qkv + (size_t)(c*256 + rg*64 + jj)*3840 + n*64 + seg*16);
    *(uint4*)&q_s[jj][seg*16]   = src[0];
    *(uint4*)&q_s[jj][seg*16+8] = src[1];
  }
  #pragma unroll
  for (int p=0;p<3;p++){
    int j = tid + p*256;
    int kpos = c*256 + j - 256;
    int ok = 0;
    if (kpos >= 0 && kpos < 2048) ok = (amask[kpos] != 0) && (gmask[kpos] == 0);
    okk_s[j] = ok;
  }
  if (tid < 64)       kv0[0][tid]    = b2f(qkv[768  + n*64 + tid]);
  else if (tid < 128) kv0[1][tid-64] = b2f(qkv[1536 + n*64 + (tid-64)]);

  auto loadK = [&](int kt, uint4& a, uint4& b){
    int kpos = c*256 + kt*64 + jj - 256;
    int kq = kpos < 0 ? 0 : (kpos > 2047 ? 2047 : kpos);
    const uint4* ks = (const uint4*)(qkv + (size_t)kq*3840 + 768 + n*64 + seg*16);
    a = ks[0]; b = ks[1];
  };
  auto loadV = [&](int kt, uint4& a, uint4& b){
    int base = c*256 + kt*64 - 256;
    int sb = (base < 0 || base > 2048-64) ? 0 : base;
    const uint4* vs = (const uint4*)(Vt + (size_t)(n*64 + jj)*2048 + sb + seg*8);
    a = vs[0]; b = vs[4];
  };

  const int kt_lo = (c==0) ? ((rg > 4) ? rg : 4) : rg;
  int kt_hi = rg+8 < 11 ? rg+8 : 11;
  const int clip = (2303 - c*256) >> 6;
  if (kt_hi > clip) kt_hi = clip;

  uint4 ka,kb,va,vb;
  loadK(kt_lo,ka,kb); loadV(kt_lo,va,vb);
  *(uint4*)&k_s[0][jj][seg*16]    = ka;
  *(uint4*)&k_s[0][jj][seg*16+8]  = kb;
  *(uint4*)&vt_s[0][jj][seg*8]    = va;
  *(uint4*)&vt_s[0][jj][seg*8+32] = vb;

  float lsum[4];
  f32x4 out[4];
  const f32x4 zero = {0.f,0.f,0.f,0.f};
  #pragma unroll
  for (int r=0;r<4;r++) lsum[r] = 0.f;
  #pragma unroll
  for (int dt=0;dt<4;dt++) out[dt] = zero;

  int cur = 0;
  for (int kt = kt_lo; kt <= kt_hi; kt++) {
    const bool pf = (kt < kt_hi);
    if (pf){ loadK(kt+1,ka,kb); loadV(kt+1,va,vb); }
    __syncthreads();

    f32x4 s[4];
    #pragma unroll
    for (int ct=0;ct<4;ct++) s[ct] = zero;
    __builtin_amdgcn_s_setprio(1);
    #pragma unroll
    for (int ks=0;ks<2;ks++){
      bf16x8 aq = *reinterpret_cast<const bf16x8*>(&q_s[wave*16 + fr][ks*32 + fk*8]);
      #pragma unroll
      for (int ct=0;ct<4;ct++){
        bf16x8 bk = *reinterpret_cast<const bf16x8*>(&k_s[cur][ct*16 + fr][ks*32 + fk*8]);
        s[ct] = __builtin_amdgcn_mfma_f32_16x16x32_bf16(aq, bk, s[ct], 0,0,0);
      }
    }
    __builtin_amdgcn_s_setprio(0);
    const int qbase = rg*64 + wave*16 + fk*4;
    #pragma unroll
    for (int ct=0;ct<4;ct++){
      int j = kt*64 + ct*16 + fr;
      int okj = okk_s[j];
      #pragma unroll
      for (int r=0;r<4;r++){
        unsigned rel = (unsigned)(j - (qbase + r));
        float sv = (okj && rel <= 512u) ? s[ct][r] : -kNEG;
        float p = __expf(sv);
        lsum[r] += p;
        p_s[wave][fk*4 + r][ct*16 + fr] = f2b(p);
      }
    }
    __builtin_amdgcn_s_setprio(1);
    #pragma unroll
    for (int ks=0;ks<2;ks++){
      bf16x8 ap = *reinterpret_cast<const bf16x8*>(&p_s[wave][fr][ks*32 + fk*8]);
      #pragma unroll
      for (int dt=0;dt<4;dt++){
        bf16x8 bv = *reinterpret_cast<const bf16x8*>(&vt_s[cur][dt*16 + fr][ks*32 + fk*8]);
        out[dt] = __builtin_amdgcn_mfma_f32_16x16x32_bf16(ap, bv, out[dt], 0,0,0);
      }
    }
    __builtin_amdgcn_s_setprio(0);

    if (pf){
      *(uint4*)&k_s[cur^1][jj][seg*16]    = ka;
      *(uint4*)&k_s[cur^1][jj][seg*16+8]  = kb;
      *(uint4*)&vt_s[cur^1][jj][seg*8]    = va;
      *(uint4*)&vt_s[cur^1][jj][seg*8+32] = vb;
      cur ^= 1;
    }
  }

  const bool okg = (amask[0] != 0);
  #pragma unroll
  for (int r=0;r<4;r++){
    const int row16 = fk*4 + r;
    float ts = lsum[r];
    #pragma unroll
    for (int mk=8; mk>=1; mk>>=1) ts += __shfl_xor(ts, mk);
    float sp = 0.f;
    #pragma unroll
    for (int e=0;e<4;e++){
      int d = fr*4 + e;
      sp += b2f(q_s[wave*16 + row16][d]) * kv0[0][d];
    }
    #pragma unroll
    for (int mk=8; mk>=1; mk>>=1) sp += __shfl_xor(sp, mk);
    float pg = okg ? __expf(sp) : 0.f;
    float lf = ts + pg;
    const int srow = c*256 + rg*64 + wave*16 + row16;
    if (srow != 0) {
      #pragma unroll
      for (int dt=0;dt<4;dt++){
        int d = dt*16 + fr;
        float o = (out[dt][r] + pg*kv0[1][d]) / lf;
        attn[(size_t)srow*768 + n*64 + d] = f2b(o);
      }
    }
  }
}

// ---------------- head, parallelized: 3 small kernels ----------------
__global__ __launch_bounds__(256)
void head_p1(const float* __restrict__ h0, const float* __restrict__ dw,
             float* __restrict__ pd)
{
  const int col = blockIdx.x*256 + threadIdx.x;
  const int z = blockIdx.y;
  const int k0 = z*96;
  float acc = 0.f;
  #pragma unroll 8
  for (int k=0;k<96;k++) acc += h0[k0+k]*dw[(size_t)(k0+k)*768 + col];
  pd[z*768 + col] = acc;
}

// p2: block z reduces pd for its 96-wide k-slice -> tanh -> LDS, then partials of y@ow
__global__ __launch_bounds__(256)
void head_p2(const float* __restrict__ pd, const float* __restrict__ db,
             const float* __restrict__ ow, float* __restrict__ po)
{
  __shared__ float yl[96];
  const int tid = threadIdx.x;
  const int z = blockIdx.x;
  const int k0 = z*96;
  if (tid < 96) {
    float a = 0.f;
    #pragma unroll
    for (int zz=0;zz<8;zz++) a += pd[zz*768 + k0 + tid];
    yl[tid] = tanhf(a + db[k0 + tid]);
  }
  __syncthreads();
  const int col = tid;
  float acc = 0.f;
  #pragma unroll 8
  for (int k=0;k<96;k++) acc += yl[k]*ow[(size_t)(k0+k)*256 + col];
  po[z*256 + col] = acc;
}

__global__ __launch_bounds__(256)
void head_fin(const float* __restrict__ po, const float* __restrict__ ob,
              float* __restrict__ out)
{
  const int col = threadIdx.x;
  float a = 0.f;
  #pragma unroll
  for (int z=0;z<8;z++) a += po[z*256 + col];
  out[col] = a + ob[col];
}

// ---------------- host ----------------
extern "C" void kernel_launch(void* const* d_in, const int* in_sizes, int n_in,
                              void* d_out, int out_size, void* d_ws, size_t ws_size,
                              hipStream_t stream)
{
  const int*   ids   = (const int*)d_in[0];
  const int*   amask = (const int*)d_in[1];
  const int*   gmask = (const int*)d_in[2];
  const float* wemb  = (const float*)d_in[3];
  const float* pemb  = (const float*)d_in[4];
  const float* elns  = (const float*)d_in[5];
  const float* elnb  = (const float*)d_in[6];
  const float* Wq    = (const float*)d_in[7];
  const float* bq    = (const float*)d_in[8];
  const float* Wk    = (const float*)d_in[9];
  const float* bk    = (const float*)d_in[10];
  const float* Wv    = (const float*)d_in[11];
  const float* bv    = (const float*)d_in[12];
  const float* Wqg   = (const float*)d_in[13];
  const float* bqg   = (const float*)d_in[14];
  const float* Wkg   = (const float*)d_in[15];
  const float* bkg   = (const float*)d_in[16];
  const float* Wvg   = (const float*)d_in[17];
  const float* bvg   = (const float*)d_in[18];
  const float* Wo    = (const float*)d_in[19];
  const float* bo    = (const float*)d_in[20];
  const float* ln1s  = (const float*)d_in[21];
  const float* ln1b  = (const float*)d_in[22];
  const float* Wf1   = (const float*)d_in[23];
  const float* bf1   = (const float*)d_in[24];
  const float* Wf2   = (const float*)d_in[25];
  const float* bf2   = (const float*)d_in[26];
  const float* ln2s  = (const float*)d_in[27];
  const float* ln2b  = (const float*)d_in[28];
  const float* dw    = (const float*)d_in[29];
  const float* db    = (const float*)d_in[30];
  const float* ow    = (const float*)d_in[31];
  const float* ob    = (const float*)d_in[32];

  char* ws = (char*)d_ws;
  size_t off = 0;
  auto alloc = [&](size_t bytes)->char*{
    char* p = ws + off; off += (bytes + 255) & ~(size_t)255; return p;
  };
  float* h     = (float*)alloc((size_t)2048*768*4);
  bf16*  hb    = (bf16*) alloc((size_t)2048*768*2);
  float* h2    = (float*)alloc((size_t)2048*768*4);
  bf16*  h2b   = (bf16*) alloc((size_t)2048*768*2);
  bf16*  qkv   = (bf16*) alloc((size_t)2048*3840*2);
  bf16*  att   = (bf16*) alloc((size_t)2048*768*2);
  bf16*  f1    = (bf16*) alloc((size_t)2048*3072*2);
  bf16*  Vtb   = (bf16*) alloc((size_t)768*2048*2);    // V^T per layer [head*64+d][s]
  bf16*  pfb   = (bf16*) alloc((size_t)4*2048*768*2);  // split-K partials (bf16)
  bf16*  WcatT = (bf16*) alloc((size_t)12*5*768*768*2);
  bf16*  WoT   = (bf16*) alloc((size_t)12*768*768*2);
  bf16*  Wf1T  = (bf16*) alloc((size_t)12*768*3072*2);
  bf16*  Wf2T  = (bf16*) alloc((size_t)12*768*3072*2);
  float* bcat  = (float*)alloc((size_t)12*3840*4);
  float* pd    = (float*)alloc((size_t)8*768*4);
  float* po    = (float*)alloc((size_t)8*256*4);

  prep_all<<<dim3(519,12),256,0,stream>>>(Wq, Wk, Wv, Wkg, Wvg, Wo, Wf1, Wf2,
                                          bq, bk, bv, bkg, bvg,
                                          WcatT, WoT, Wf1T, Wf2T, bcat);
  embed_ln<<<2048,192,0,stream>>>(ids, wemb, pemb, elns, elnb, h, hb);

  for (int l=0; l<12; l++) {
    const size_t oHH = (size_t)l*768*768;
    const size_t oH  = (size_t)l*768;
    const size_t oF  = (size_t)l*3072;
    const bf16* WcatT_l = WcatT + (size_t)l*5*768*768;
    const bf16* WoT_l   = WoT   + (size_t)l*768*768;
    const bf16* Wf1T_l  = Wf1T  + (size_t)l*768*3072;
    const bf16* Wf2T_l  = Wf2T  + (size_t)l*768*3072;
    const float* bcat_l = bcat  + (size_t)l*3840;

    gemm_bt<0,1,0,1,1><<<dim3(16,30),256,0,stream>>>(hb, WcatT_l, bcat_l, nullptr, qkv,
                                                     Vtb, 2048, 3840, 768);
    band_attn<<<dim3(8,12,5),256,0,stream>>>(qkv, Vtb, h, Wqg+oHH, bqg+oH,
                                             amask, gmask, att);
    gemm_bt<1,0,0,3,0><<<dim3(16,6,3),256,0,stream>>>(att, WoT_l, bo+oH, pfb, nullptr,
                                                      nullptr, 2048, 768, 768);
    add_ln<3><<<2048,192,0,stream>>>(h, pfb, ln1s+oH, ln1b+oH, h2, h2b);
    gemm_bt<0,1,1,1,0><<<dim3(16,24),256,0,stream>>>(h2b, Wf1T_l, bf1+oF, nullptr, f1,
                                                     nullptr, 2048, 3072, 768);
    gemm_bt<1,0,0,3,0><<<dim3(16,6,3),256,0,stream>>>(f1, Wf2T_l, bf2+oH, pfb, nullptr,
                                                      nullptr, 2048, 768, 3072);
    add_ln<3><<<2048,192,0,stream>>>(h2, pfb, ln2s+oH, ln2b+oH, h, hb);
  }

  head_p1<<<dim3(3,8),256,0,stream>>>(h, dw, pd);
  head_p2<<<8,256,0,stream>>>(pd, db, ow, po);
  head_fin<<<1,256,0,stream>>>(po, ob, (float*)d_out);
}